// Round 2
// baseline (538.001 us; speedup 1.0000x reference)
//
#include <hip/hip_runtime.h>

#define NN 100000
#define NE 1600000
#define NM 10000
#define NSLICE 8
#define SLICE ((NN + NSLICE - 1) / NSLICE)   // 12500

__device__ inline float4 ld4(const float* p) { return *(const float4*)p; }
__device__ inline void st4(float* p, float4 v) { *(float4*)p = v; }
__device__ inline float4 relu4(float4 v) {
  v.x = fmaxf(v.x, 0.f); v.y = fmaxf(v.y, 0.f);
  v.z = fmaxf(v.z, 0.f); v.w = fmaxf(v.w, 0.f);
  return v;
}

// ---------- degree count, dst-range sliced (XCD-local atomics & lines) ----------
__global__ __launch_bounds__(256) void deg_count_k(const int* __restrict__ dst,
                                                   int* __restrict__ deg) {
  const int slice = blockIdx.x & (NSLICE - 1);
  const int lo = slice * SLICE;
  const int hi = min(lo + SLICE, NN);
  const int nb = gridDim.x / NSLICE;
  const int bid = blockIdx.x / NSLICE;
  for (int e = bid * 256 + threadIdx.x; e < NE; e += nb * 256) {
    int d = dst[e];
    if (d >= lo && d < hi) atomicAdd(&deg[d], 1);
  }
}

__global__ __launch_bounds__(1024) void scan1_k(const int* __restrict__ deg,
                                                int* __restrict__ excl,
                                                int* __restrict__ bsum, int n) {
  __shared__ int lds[1024];
  int tid = threadIdx.x;
  int gid = blockIdx.x * 1024 + tid;
  int v = (gid < n) ? deg[gid] : 0;
  lds[tid] = v;
  __syncthreads();
  for (int off = 1; off < 1024; off <<= 1) {
    int t = (tid >= off) ? lds[tid - off] : 0;
    __syncthreads();
    lds[tid] += t;
    __syncthreads();
  }
  if (gid < n) excl[gid] = lds[tid] - v;   // block-local exclusive scan
  if (tid == 1023) bsum[blockIdx.x] = lds[1023];
}

__global__ void scan2_k(int* __restrict__ bsum, int nb) {
  if (threadIdx.x == 0 && blockIdx.x == 0) {
    int run = 0;
    for (int i = 0; i < nb; ++i) { int t = bsum[i]; bsum[i] = run; run += t; }
  }
}

// scan finalize + cursor init + inv_deg, fused
__global__ __launch_bounds__(256) void scan3_k(int* __restrict__ excl,
                                               const int* __restrict__ bsum,
                                               int* __restrict__ cursor,
                                               const int* __restrict__ deg,
                                               float* __restrict__ inv, int n) {
  int gid = blockIdx.x * 256 + threadIdx.x;
  if (gid < n) {
    int v = excl[gid] + bsum[gid >> 10];
    excl[gid] = v;
    cursor[gid] = v;
    inv[gid] = 1.0f / fmaxf((float)deg[gid], 1.0f);
  }
}

// ---------- CSR fill, dst-range sliced ----------
__global__ __launch_bounds__(256) void csr_build_k(const int* __restrict__ src,
                                                   const int* __restrict__ dst,
                                                   int* __restrict__ cursor,
                                                   int* __restrict__ csr) {
  const int slice = blockIdx.x & (NSLICE - 1);
  const int lo = slice * SLICE;
  const int hi = min(lo + SLICE, NN);
  const int nb = gridDim.x / NSLICE;
  const int bid = blockIdx.x / NSLICE;
  for (int e = bid * 256 + threadIdx.x; e < NE; e += nb * 256) {
    int d = dst[e];
    if (d >= lo && d < hi) {
      int p = atomicAdd(&cursor[d], 1);
      csr[p] = src[e];
    }
  }
}

// ---------- dense GEMM: Y[r][c] = sum_k X[r][k]*W[k][c], 128 cols, 32-row tiles ----------
template<bool ACC, bool BIAS, bool RELU>
__global__ __launch_bounds__(256) void gemm128(const float* __restrict__ X, int ldx,
                                               const float* __restrict__ W,
                                               const float* __restrict__ bias,
                                               float* __restrict__ Y, int nrows) {
  __shared__ float Wlds[128 * 128];   // 64 KB
  __shared__ float Xlds[32 * 128];    // 16 KB
  const int tid = threadIdx.x;
  for (int i = tid; i < 128 * 128 / 4; i += 256)
    ((float4*)Wlds)[i] = ((const float4*)W)[i];
  const int cq = (tid & 31) * 4;   // 4 output columns
  const int s = tid >> 5;          // row slot: rows s, s+8, s+16, s+24
  const int ngroups = (nrows + 31) >> 5;
  for (int g = blockIdx.x; g < ngroups; g += gridDim.x) {
    const int rbase = g << 5;
    __syncthreads();               // protects Xlds reuse (and W on first iter)
    for (int i = tid; i < 32 * 32; i += 256) {
      int r = i >> 5, k4 = (i & 31) << 2;
      int row = rbase + r;
      float4 v = (row < nrows) ? ld4(X + (size_t)row * ldx + k4)
                               : make_float4(0.f, 0.f, 0.f, 0.f);
      st4(Xlds + r * 128 + k4, v);
    }
    __syncthreads();
    float4 acc[4];
#pragma unroll
    for (int r = 0; r < 4; ++r) acc[r] = make_float4(0.f, 0.f, 0.f, 0.f);
#pragma unroll 8
    for (int k = 0; k < 128; k += 4) {
      float4 w0 = ld4(Wlds + (k + 0) * 128 + cq);
      float4 w1 = ld4(Wlds + (k + 1) * 128 + cq);
      float4 w2 = ld4(Wlds + (k + 2) * 128 + cq);
      float4 w3 = ld4(Wlds + (k + 3) * 128 + cq);
#pragma unroll
      for (int r = 0; r < 4; ++r) {
        float4 x = ld4(Xlds + (s + 8 * r) * 128 + k);
        float4 a = acc[r];
        a.x = fmaf(x.x, w0.x, a.x); a.y = fmaf(x.x, w0.y, a.y);
        a.z = fmaf(x.x, w0.z, a.z); a.w = fmaf(x.x, w0.w, a.w);
        a.x = fmaf(x.y, w1.x, a.x); a.y = fmaf(x.y, w1.y, a.y);
        a.z = fmaf(x.y, w1.z, a.z); a.w = fmaf(x.y, w1.w, a.w);
        a.x = fmaf(x.z, w2.x, a.x); a.y = fmaf(x.z, w2.y, a.y);
        a.z = fmaf(x.z, w2.z, a.z); a.w = fmaf(x.z, w2.w, a.w);
        a.x = fmaf(x.w, w3.x, a.x); a.y = fmaf(x.w, w3.y, a.y);
        a.z = fmaf(x.w, w3.z, a.z); a.w = fmaf(x.w, w3.w, a.w);
        acc[r] = a;
      }
    }
#pragma unroll
    for (int r = 0; r < 4; ++r) {
      int row = rbase + s + 8 * r;
      if (row < nrows) {
        float* y = Y + (size_t)row * 128 + cq;
        float4 o = acc[r];
        if (ACC) { float4 p = ld4(y); o.x += p.x; o.y += p.y; o.z += p.z; o.w += p.w; }
        if (BIAS) { float4 b = ld4(bias + cq); o.x += b.x; o.y += b.y; o.z += b.z; o.w += b.w; }
        if (RELU) o = relu4(o);
        st4(y, o);
      }
    }
  }
}

// ---------- CSR gather-aggregate: out[v] = post(inv[v]*sum_{s in N(v)} hw[s] + b) ----------
template<bool RELU>
__global__ __launch_bounds__(256) void gather_agg_k(const float* __restrict__ hw,
                                                    const int* __restrict__ csr,
                                                    const int* __restrict__ offs,
                                                    const int* __restrict__ degv,
                                                    const float* __restrict__ inv,
                                                    const float* __restrict__ bias,
                                                    float* __restrict__ out) {
  int v = blockIdx.x * 8 + (threadIdx.x >> 5);
  if (v >= NN) return;
  int lane = threadIdx.x & 31;
  int start = offs[v], cnt = degv[v];
  float4 acc = make_float4(0.f, 0.f, 0.f, 0.f);
  for (int i = 0; i < cnt; ++i) {
    int sv = csr[start + i];
    float4 x = ld4(hw + (size_t)sv * 128 + lane * 4);
    acc.x += x.x; acc.y += x.y; acc.z += x.z; acc.w += x.w;
  }
  float iv = inv[v];
  float4 b = ld4(bias + lane * 4);
  float4 o;
  o.x = fmaf(acc.x, iv, b.x); o.y = fmaf(acc.y, iv, b.y);
  o.z = fmaf(acc.z, iv, b.z); o.w = fmaf(acc.w, iv, b.w);
  if (RELU) o = relu4(o);
  st4(out + (size_t)v * 128 + lane * 4, o);
}

// ---------- layer-2 aggregate only at masked nodes, fused relu + concat ----------
__global__ __launch_bounds__(256) void gather_masked_k(const float* __restrict__ hw2,
                                                       const float* __restrict__ feat,
                                                       const int* __restrict__ masked,
                                                       const int* __restrict__ csr,
                                                       const int* __restrict__ offs,
                                                       const int* __restrict__ degv,
                                                       const float* __restrict__ inv,
                                                       const float* __restrict__ b2,
                                                       float* __restrict__ xcat) {
  int m = blockIdx.x * 8 + (threadIdx.x >> 5);
  if (m >= NM) return;
  int lane = threadIdx.x & 31;
  int v = masked[m];
  int start = offs[v], cnt = degv[v];
  float4 acc = make_float4(0.f, 0.f, 0.f, 0.f);
  for (int i = 0; i < cnt; ++i) {
    int sv = csr[start + i];
    float4 x = ld4(hw2 + (size_t)sv * 128 + lane * 4);
    acc.x += x.x; acc.y += x.y; acc.z += x.z; acc.w += x.w;
  }
  float iv = inv[v];
  float4 b = ld4(b2 + lane * 4);
  float4 o;
  o.x = fmaf(acc.x, iv, b.x); o.y = fmaf(acc.y, iv, b.y);
  o.z = fmaf(acc.z, iv, b.z); o.w = fmaf(acc.w, iv, b.w);
  o = relu4(o);
  st4(xcat + (size_t)m * 256 + lane * 4, o);
  st4(xcat + (size_t)m * 256 + 128 + lane * 4, ld4(feat + (size_t)v * 128 + lane * 4));
}

extern "C" void kernel_launch(void* const* d_in, const int* in_sizes, int n_in,
                              void* d_out, int out_size, void* d_ws, size_t ws_size,
                              hipStream_t stream) {
  const float* feat = (const float*)d_in[0];
  const int* src = (const int*)d_in[1];
  const int* dst = (const int*)d_in[2];
  const int* masked = (const int*)d_in[3];
  const float* W1 = (const float*)d_in[4];
  const float* b1 = (const float*)d_in[5];
  const float* W2 = (const float*)d_in[6];
  const float* b2 = (const float*)d_in[7];
  const float* Wm1 = (const float*)d_in[8];
  const float* bm1 = (const float*)d_in[9];
  const float* Wm2 = (const float*)d_in[10];
  const float* bm2 = (const float*)d_in[11];
  const float* Wm3 = (const float*)d_in[12];
  float* out = (float*)d_out;

  // workspace layout
  int* deg = (int*)d_ws;                 // NN
  int* offs = deg + NN;                  // NN
  int* cursor = offs + NN;               // NN
  int* csr = cursor + NN;                // NE
  int* bsum = csr + NE;                  // 128
  float* inv = (float*)(bsum + 128);     // NN
  float* A = inv + NN;                   // NN*128
  float* B = A + (size_t)NN * 128;       // NN*128

  hipMemsetAsync(deg, 0, NN * sizeof(int), stream);
  deg_count_k<<<2048, 256, 0, stream>>>(dst, deg);
  int nb = (NN + 1023) / 1024;
  scan1_k<<<nb, 1024, 0, stream>>>(deg, offs, bsum, NN);
  scan2_k<<<1, 64, 0, stream>>>(bsum, nb);
  scan3_k<<<(NN + 255) / 256, 256, 0, stream>>>(offs, bsum, cursor, deg, inv, NN);
  csr_build_k<<<2048, 256, 0, stream>>>(src, dst, cursor, csr);

  // GCN layer 1: A = feat @ W1 ; B = relu(inv * agg(A) + b1)
  gemm128<false, false, false><<<512, 256, 0, stream>>>(feat, 128, W1, nullptr, A, NN);
  gather_agg_k<true><<<(NN + 7) / 8, 256, 0, stream>>>(A, csr, offs, deg, inv, b1, B);
  // GCN layer 2 (only masked dst needed): A = B @ W2 ; B[:, :256] = [relu(h2[mask]), feat[mask]]
  gemm128<false, false, false><<<512, 256, 0, stream>>>(B, 128, W2, nullptr, A, NN);
  gather_masked_k<<<(NM + 7) / 8, 256, 0, stream>>>(A, feat, masked, csr, offs, deg, inv, b2, B);

  // MLP head on M rows: split K=256 into two K=128 passes
  gemm128<false, false, false><<<512, 256, 0, stream>>>(B, 256, Wm1, nullptr, A, NM);
  gemm128<true, true, true><<<512, 256, 0, stream>>>(B + 128, 256, Wm1 + 128 * 128, bm1, A, NM);
  gemm128<false, true, true><<<512, 256, 0, stream>>>(A, 128, Wm2, bm2, B, NM);
  gemm128<false, false, false><<<512, 256, 0, stream>>>(B, 128, Wm3, nullptr, out, NM);
}

// Round 4
// 345.494 us; speedup vs baseline: 1.5572x; 1.5572x over previous
//
#include <hip/hip_runtime.h>

#define NN 100000
#define NE 1600000
#define NM 10000
#define NSLICE 8
#define SLICE ((NN + NSLICE - 1) / NSLICE)

typedef __attribute__((ext_vector_type(8))) short bf16x8;
typedef __attribute__((ext_vector_type(4))) float f32x4;

__device__ inline float4 ld4(const float* p) { return *(const float4*)p; }
__device__ inline void st4(float* p, float4 v) { *(float4*)p = v; }
__device__ inline float4 relu4(float4 v) {
  v.x = fmaxf(v.x, 0.f); v.y = fmaxf(v.y, 0.f);
  v.z = fmaxf(v.z, 0.f); v.w = fmaxf(v.w, 0.f);
  return v;
}
__device__ inline float bf2f(unsigned short u) {
  union { unsigned int i; float f; } c; c.i = ((unsigned int)u) << 16; return c.f;
}
__device__ inline unsigned short f2bf(float f) {
  union { float f; unsigned int i; } c; c.f = f;
  unsigned int u = c.i + 0x7fffu + ((c.i >> 16) & 1u);
  return (unsigned short)(u >> 16);
}
__device__ inline void acc4(float& a0, float& a1, float& a2, float& a3, uint2 u) {
  a0 += bf2f((unsigned short)(u.x));
  a1 += bf2f((unsigned short)(u.x >> 16));
  a2 += bf2f((unsigned short)(u.y));
  a3 += bf2f((unsigned short)(u.y >> 16));
}

// ---------- degree count, dst-range sliced ----------
__global__ __launch_bounds__(256) void deg_count_k(const int* __restrict__ dst,
                                                   int* __restrict__ deg) {
  const int slice = blockIdx.x & (NSLICE - 1);
  const int lo = slice * SLICE;
  const int hi = min(lo + SLICE, NN);
  const int nb = gridDim.x / NSLICE;
  const int bid = blockIdx.x / NSLICE;
  for (int e = bid * 256 + threadIdx.x; e < NE; e += nb * 256) {
    int d = dst[e];
    if (d >= lo && d < hi) atomicAdd(&deg[d], 1);
  }
}

__global__ __launch_bounds__(1024) void scan1_k(const int* __restrict__ deg,
                                                int* __restrict__ excl,
                                                int* __restrict__ bsum, int n) {
  __shared__ int lds[1024];
  int tid = threadIdx.x;
  int gid = blockIdx.x * 1024 + tid;
  int v = (gid < n) ? deg[gid] : 0;
  lds[tid] = v;
  __syncthreads();
  for (int off = 1; off < 1024; off <<= 1) {
    int t = (tid >= off) ? lds[tid - off] : 0;
    __syncthreads();
    lds[tid] += t;
    __syncthreads();
  }
  if (gid < n) excl[gid] = lds[tid] - v;
  if (tid == 1023) bsum[blockIdx.x] = lds[1023];
}

// exclusive scan of up to 128 block sums
__global__ void scan2_k(int* __restrict__ bsum, int nb) {
  __shared__ int lds[128];
  int tid = threadIdx.x;
  int v = (tid < nb) ? bsum[tid] : 0;
  lds[tid] = v;
  __syncthreads();
  for (int off = 1; off < 128; off <<= 1) {
    int t = (tid >= off) ? lds[tid - off] : 0;
    __syncthreads();
    lds[tid] += t;
    __syncthreads();
  }
  if (tid < nb) bsum[tid] = lds[tid] - v;
}

__global__ __launch_bounds__(256) void scan3_k(int* __restrict__ excl,
                                               const int* __restrict__ bsum,
                                               int* __restrict__ cursor,
                                               const int* __restrict__ deg,
                                               float* __restrict__ inv, int n) {
  int gid = blockIdx.x * 256 + threadIdx.x;
  if (gid < n) {
    int v = excl[gid] + bsum[gid >> 10];
    excl[gid] = v;
    cursor[gid] = v;
    inv[gid] = 1.0f / fmaxf((float)deg[gid], 1.0f);
  }
}

// ---------- CSR fill, dst-range sliced ----------
__global__ __launch_bounds__(256) void csr_build_k(const int* __restrict__ src,
                                                   const int* __restrict__ dst,
                                                   int* __restrict__ cursor,
                                                   int* __restrict__ csr) {
  const int slice = blockIdx.x & (NSLICE - 1);
  const int lo = slice * SLICE;
  const int hi = min(lo + SLICE, NN);
  const int nb = gridDim.x / NSLICE;
  const int bid = blockIdx.x / NSLICE;
  for (int e = bid * 256 + threadIdx.x; e < NE; e += nb * 256) {
    int d = dst[e];
    if (d >= lo && d < hi) {
      int p = atomicAdd(&cursor[d], 1);
      csr[p] = src[e];
    }
  }
}

// ---------- fp32 -> bf16 bulk convert (n multiple of 4) ----------
__global__ __launch_bounds__(256) void tobf_k(const float* __restrict__ x,
                                              unsigned short* __restrict__ y, int n) {
  int idx = (blockIdx.x * 256 + threadIdx.x) * 4;
  if (idx < n) {
    float4 v = ld4(x + idx);
    unsigned int lo = (unsigned int)f2bf(v.x) | ((unsigned int)f2bf(v.y) << 16);
    unsigned int hi = (unsigned int)f2bf(v.z) | ((unsigned int)f2bf(v.w) << 16);
    *(uint2*)(y + idx) = make_uint2(lo, hi);
  }
}

// ---------- gather raw bf16 rows, fp32 accum, scale by inv, write bf16 ----------
__global__ __launch_bounds__(256) void gather1_k(const unsigned short* __restrict__ featbf,
                                                 const int* __restrict__ csr,
                                                 const int* __restrict__ offs,
                                                 const int* __restrict__ degv,
                                                 const float* __restrict__ inv,
                                                 unsigned short* __restrict__ agg1) {
  int v = blockIdx.x * 8 + (threadIdx.x >> 5);
  if (v >= NN) return;
  int lane = threadIdx.x & 31;
  int start = offs[v], cnt = degv[v];
  const uint2* fb = (const uint2*)featbf;     // 4 bf16 per uint2, 32 per row
  float a0 = 0.f, a1 = 0.f, a2 = 0.f, a3 = 0.f;
  int i = 0;
  for (; i + 4 <= cnt; i += 4) {
    int s0 = csr[start + i], s1 = csr[start + i + 1];
    int s2 = csr[start + i + 2], s3 = csr[start + i + 3];
    uint2 x0 = fb[(size_t)s0 * 32 + lane];
    uint2 x1 = fb[(size_t)s1 * 32 + lane];
    uint2 x2 = fb[(size_t)s2 * 32 + lane];
    uint2 x3 = fb[(size_t)s3 * 32 + lane];
    acc4(a0, a1, a2, a3, x0);
    acc4(a0, a1, a2, a3, x1);
    acc4(a0, a1, a2, a3, x2);
    acc4(a0, a1, a2, a3, x3);
  }
  for (; i < cnt; ++i) {
    uint2 x = fb[(size_t)csr[start + i] * 32 + lane];
    acc4(a0, a1, a2, a3, x);
  }
  float iv = inv[v];
  unsigned int lo = (unsigned int)f2bf(a0 * iv) | ((unsigned int)f2bf(a1 * iv) << 16);
  unsigned int hi = (unsigned int)f2bf(a2 * iv) | ((unsigned int)f2bf(a3 * iv) << 16);
  ((uint2*)agg1)[(size_t)v * 32 + lane] = make_uint2(lo, hi);
}

// ---------- MFMA bf16 GEMM: H = relu(A @ W + b), A[n][128] bf16, out bf16 ----------
__global__ __launch_bounds__(256) void gemm1_mfma_k(const unsigned short* __restrict__ Abf,
                                                    const unsigned short* __restrict__ Wbf,
                                                    const float* __restrict__ bias,
                                                    unsigned short* __restrict__ Hbf,
                                                    int nrows) {
  const int tid = threadIdx.x;
  const int wave = tid >> 6;      // 0..3  -> col-tiles wave, wave+4
  const int lane = tid & 63;
  const int l15 = lane & 15;
  const int l4 = lane >> 4;       // k-octet 0..3
  const int rbase = blockIdx.x * 64;

  bf16x8 Bfr[2][4];
#pragma unroll
  for (int c = 0; c < 2; ++c) {
    int col = (wave + 4 * c) * 16 + l15;
#pragma unroll
    for (int kt = 0; kt < 4; ++kt) {
      bf16x8 b;
#pragma unroll
      for (int i = 0; i < 8; ++i)
        b[i] = (short)Wbf[(kt * 32 + l4 * 8 + i) * 128 + col];
      Bfr[c][kt] = b;
    }
  }
  float bias0 = bias[wave * 16 + l15];
  float bias1 = bias[(wave + 4) * 16 + l15];

  for (int rsub = 0; rsub < 4; ++rsub) {
    int arow = rbase + rsub * 16 + l15;
    const unsigned short* ap = Abf + (size_t)(arow < nrows ? arow : 0) * 128;
    bf16x8 Afr[4];
#pragma unroll
    for (int kt = 0; kt < 4; ++kt)
      Afr[kt] = *(const bf16x8*)(ap + kt * 32 + l4 * 8);
    f32x4 acc0 = {0.f, 0.f, 0.f, 0.f};
    f32x4 acc1 = {0.f, 0.f, 0.f, 0.f};
#pragma unroll
    for (int kt = 0; kt < 4; ++kt) {
      acc0 = __builtin_amdgcn_mfma_f32_16x16x32_bf16(Afr[kt], Bfr[0][kt], acc0, 0, 0, 0);
      acc1 = __builtin_amdgcn_mfma_f32_16x16x32_bf16(Afr[kt], Bfr[1][kt], acc1, 0, 0, 0);
    }
    // D layout: col = l15, row = l4*4 + r  (within 16x16 tile)
#pragma unroll
    for (int r = 0; r < 4; ++r) {
      int orow = rbase + rsub * 16 + l4 * 4 + r;
      if (orow < nrows) {
        Hbf[(size_t)orow * 128 + wave * 16 + l15] = f2bf(fmaxf(acc0[r] + bias0, 0.f));
        Hbf[(size_t)orow * 128 + (wave + 4) * 16 + l15] = f2bf(fmaxf(acc1[r] + bias1, 0.f));
      }
    }
  }
}

// ---------- layer-2 aggregate at masked nodes (bf16 in, fp32 out) + feat concat ----------
__global__ __launch_bounds__(256) void gather2_k(const unsigned short* __restrict__ h1bf,
                                                 const float* __restrict__ feat,
                                                 const int* __restrict__ masked,
                                                 const int* __restrict__ csr,
                                                 const int* __restrict__ offs,
                                                 const int* __restrict__ degv,
                                                 const float* __restrict__ inv,
                                                 float* __restrict__ agg2,
                                                 float* __restrict__ xcat) {
  int m = blockIdx.x * 8 + (threadIdx.x >> 5);
  if (m >= NM) return;
  int lane = threadIdx.x & 31;
  int v = masked[m];
  int start = offs[v], cnt = degv[v];
  const uint2* fb = (const uint2*)h1bf;
  float a0 = 0.f, a1 = 0.f, a2 = 0.f, a3 = 0.f;
  int i = 0;
  for (; i + 4 <= cnt; i += 4) {
    int s0 = csr[start + i], s1 = csr[start + i + 1];
    int s2 = csr[start + i + 2], s3 = csr[start + i + 3];
    uint2 x0 = fb[(size_t)s0 * 32 + lane];
    uint2 x1 = fb[(size_t)s1 * 32 + lane];
    uint2 x2 = fb[(size_t)s2 * 32 + lane];
    uint2 x3 = fb[(size_t)s3 * 32 + lane];
    acc4(a0, a1, a2, a3, x0);
    acc4(a0, a1, a2, a3, x1);
    acc4(a0, a1, a2, a3, x2);
    acc4(a0, a1, a2, a3, x3);
  }
  for (; i < cnt; ++i) {
    uint2 x = fb[(size_t)csr[start + i] * 32 + lane];
    acc4(a0, a1, a2, a3, x);
  }
  float iv = inv[v];
  st4(agg2 + (size_t)m * 128 + lane * 4, make_float4(a0 * iv, a1 * iv, a2 * iv, a3 * iv));
  st4(xcat + (size_t)m * 256 + 128 + lane * 4, ld4(feat + (size_t)v * 128 + lane * 4));
}

// ---------- fp32 GEMM (small, MLP head): Y = post(X @ W (+bias)(relu)), 128 cols ----------
template<bool ACC, bool BIAS, bool RELU>
__global__ __launch_bounds__(256) void gemm128(const float* __restrict__ X, int ldx,
                                               const float* __restrict__ W,
                                               const float* __restrict__ bias,
                                               float* __restrict__ Y, int ldy, int nrows) {
  __shared__ float Wlds[128 * 128];
  __shared__ float Xlds[32 * 128];
  const int tid = threadIdx.x;
  for (int i = tid; i < 128 * 128 / 4; i += 256)
    ((float4*)Wlds)[i] = ((const float4*)W)[i];
  const int cq = (tid & 31) * 4;
  const int s = tid >> 5;
  const int ngroups = (nrows + 31) >> 5;
  for (int g = blockIdx.x; g < ngroups; g += gridDim.x) {
    const int rbase = g << 5;
    __syncthreads();
    for (int i = tid; i < 32 * 32; i += 256) {
      int r = i >> 5, k4 = (i & 31) << 2;
      int row = rbase + r;
      float4 v = (row < nrows) ? ld4(X + (size_t)row * ldx + k4)
                               : make_float4(0.f, 0.f, 0.f, 0.f);
      st4(Xlds + r * 128 + k4, v);
    }
    __syncthreads();
    float4 acc[4];
#pragma unroll
    for (int r = 0; r < 4; ++r) acc[r] = make_float4(0.f, 0.f, 0.f, 0.f);
#pragma unroll 8
    for (int k = 0; k < 128; k += 4) {
      float4 w0 = ld4(Wlds + (k + 0) * 128 + cq);
      float4 w1 = ld4(Wlds + (k + 1) * 128 + cq);
      float4 w2 = ld4(Wlds + (k + 2) * 128 + cq);
      float4 w3 = ld4(Wlds + (k + 3) * 128 + cq);
#pragma unroll
      for (int r = 0; r < 4; ++r) {
        float4 x = ld4(Xlds + (s + 8 * r) * 128 + k);
        float4 a = acc[r];
        a.x = fmaf(x.x, w0.x, a.x); a.y = fmaf(x.x, w0.y, a.y);
        a.z = fmaf(x.x, w0.z, a.z); a.w = fmaf(x.x, w0.w, a.w);
        a.x = fmaf(x.y, w1.x, a.x); a.y = fmaf(x.y, w1.y, a.y);
        a.z = fmaf(x.y, w1.z, a.z); a.w = fmaf(x.y, w1.w, a.w);
        a.x = fmaf(x.z, w2.x, a.x); a.y = fmaf(x.z, w2.y, a.y);
        a.z = fmaf(x.z, w2.z, a.z); a.w = fmaf(x.z, w2.w, a.w);
        a.x = fmaf(x.w, w3.x, a.x); a.y = fmaf(x.w, w3.y, a.y);
        a.z = fmaf(x.w, w3.z, a.z); a.w = fmaf(x.w, w3.w, a.w);
        acc[r] = a;
      }
    }
#pragma unroll
    for (int r = 0; r < 4; ++r) {
      int row = rbase + s + 8 * r;
      if (row < nrows) {
        float* y = Y + (size_t)row * ldy + cq;
        float4 o = acc[r];
        if (ACC) { float4 p = ld4(y); o.x += p.x; o.y += p.y; o.z += p.z; o.w += p.w; }
        if (BIAS) { float4 b = ld4(bias + cq); o.x += b.x; o.y += b.y; o.z += b.z; o.w += b.w; }
        if (RELU) o = relu4(o);
        st4(y, o);
      }
    }
  }
}

extern "C" void kernel_launch(void* const* d_in, const int* in_sizes, int n_in,
                              void* d_out, int out_size, void* d_ws, size_t ws_size,
                              hipStream_t stream) {
  const float* feat = (const float*)d_in[0];
  const int* src = (const int*)d_in[1];
  const int* dst = (const int*)d_in[2];
  const int* masked = (const int*)d_in[3];
  const float* W1 = (const float*)d_in[4];
  const float* b1 = (const float*)d_in[5];
  const float* W2 = (const float*)d_in[6];
  const float* b2 = (const float*)d_in[7];
  const float* Wm1 = (const float*)d_in[8];
  const float* bm1 = (const float*)d_in[9];
  const float* Wm2 = (const float*)d_in[10];
  const float* bm2 = (const float*)d_in[11];
  const float* Wm3 = (const float*)d_in[12];
  float* out = (float*)d_out;

  // workspace layout
  int* deg = (int*)d_ws;                        // NN
  int* offs = deg + NN;                         // NN
  int* cursor = offs + NN;                      // NN
  int* csr = cursor + NN;                       // NE
  int* bsum = csr + NE;                         // 128
  float* inv = (float*)(bsum + 128);            // NN
  float* agg2 = inv + NN;                       // NM*128
  float* xcat = agg2 + (size_t)NM * 128;        // NM*256
  float* mlpA = xcat + (size_t)NM * 256;        // NM*128
  float* mlpB = mlpA + (size_t)NM * 128;        // NM*128
  unsigned short* featbf = (unsigned short*)(mlpB + (size_t)NM * 128);  // NN*128
  unsigned short* W1bf = featbf + (size_t)NN * 128;                     // 128*128
  unsigned short* agg1 = W1bf + 128 * 128;                              // NN*128
  unsigned short* h1bf = agg1 + (size_t)NN * 128;                       // NN*128

  (void)hipMemsetAsync(deg, 0, NN * sizeof(int), stream);
  deg_count_k<<<2048, 256, 0, stream>>>(dst, deg);
  int nb = (NN + 1023) / 1024;
  scan1_k<<<nb, 1024, 0, stream>>>(deg, offs, bsum, NN);
  scan2_k<<<1, 128, 0, stream>>>(bsum, nb);
  scan3_k<<<(NN + 255) / 256, 256, 0, stream>>>(offs, bsum, cursor, deg, inv, NN);
  csr_build_k<<<2048, 256, 0, stream>>>(src, dst, cursor, csr);

  tobf_k<<<(NN * 128 / 4 + 255) / 256, 256, 0, stream>>>(feat, featbf, NN * 128);
  tobf_k<<<(128 * 128 / 4 + 255) / 256, 256, 0, stream>>>(W1, W1bf, 128 * 128);

  // layer 1: agg1 = inv * agg(featbf);  h1 = relu(agg1 @ W1 + b1)  (bf16)
  gather1_k<<<(NN + 7) / 8, 256, 0, stream>>>(featbf, csr, offs, deg, inv, agg1);
  gemm1_mfma_k<<<(NN + 63) / 64, 256, 0, stream>>>(agg1, W1bf, b1, h1bf, NN);

  // layer 2 only at masked nodes: agg2 = inv * agg(h1bf); xcat = [relu(agg2@W2+b2), feat]
  gather2_k<<<(NM + 7) / 8, 256, 0, stream>>>(h1bf, feat, masked, csr, offs, deg, inv, agg2, xcat);
  int g313 = (NM + 31) / 32;
  gemm128<false, true, true><<<g313, 256, 0, stream>>>(agg2, 128, W2, b2, xcat, 256, NM);

  // MLP head (fp32): split K=256 into two K=128 passes
  gemm128<false, false, false><<<g313, 256, 0, stream>>>(xcat, 256, Wm1, nullptr, mlpA, 128, NM);
  gemm128<true, true, true><<<g313, 256, 0, stream>>>(xcat + 128, 256, Wm1 + 128 * 128, bm1, mlpA, 128, NM);
  gemm128<false, true, true><<<g313, 256, 0, stream>>>(mlpA, 128, Wm2, bm2, mlpB, 128, NM);
  gemm128<false, false, false><<<g313, 256, 0, stream>>>(mlpB, 128, Wm3, nullptr, out, 128, NM);
}

// Round 5
// 328.296 us; speedup vs baseline: 1.6388x; 1.0524x over previous
//
#include <hip/hip_runtime.h>

#define NN 100000
#define NE 1600000
#define NM 10000
#define NSLICE 8
#define SLICE ((NN + NSLICE - 1) / NSLICE)   // 12500
#define PART_CAP 216000                      // per-bucket capacity (exp 200k, sigma~420)
#define PCHUNK 2048

typedef __attribute__((ext_vector_type(8))) short bf16x8;
typedef __attribute__((ext_vector_type(4))) float f32x4;

__device__ inline float4 ld4(const float* p) { return *(const float4*)p; }
__device__ inline float bf2f(unsigned short u) {
  union { unsigned int i; float f; } c; c.i = ((unsigned int)u) << 16; return c.f;
}
__device__ inline unsigned short f2bf(float f) {
  union { float f; unsigned int i; } c; c.f = f;
  unsigned int u = c.i + 0x7fffu + ((c.i >> 16) & 1u);
  return (unsigned short)(u >> 16);
}
__device__ inline void acc4(float& a0, float& a1, float& a2, float& a3, uint2 u) {
  a0 += bf2f((unsigned short)(u.x));
  a1 += bf2f((unsigned short)(u.x >> 16));
  a2 += bf2f((unsigned short)(u.y));
  a3 += bf2f((unsigned short)(u.y >> 16));
}

// ---------- phase 1: partition edges into 8 dst-range buckets, coalesced ----------
__global__ __launch_bounds__(256) void partition_k(const int* __restrict__ src,
                                                   const int* __restrict__ dst,
                                                   uint2* __restrict__ parts,
                                                   int* __restrict__ pcnt) {
  __shared__ int cntw[4][8];
  __shared__ int basew[4][8];
  __shared__ int bstart[9];
  __shared__ int gbase[8];
  __shared__ uint2 buf[PCHUNK];
  const int tid = threadIdx.x;
  const int wv = tid >> 6;
  for (int c = 0; c < 4; ++c) {
    int e0 = (blockIdx.x * 4 + c) * PCHUNK;
    if (e0 >= NE) break;
    if (tid < 32) ((int*)cntw)[tid] = 0;
    __syncthreads();
    int s_[8], d_[8], b_[8], lp_[8];
#pragma unroll
    for (int j = 0; j < 8; ++j) {
      int e = e0 + tid * 8 + j;
      bool ok = e < NE;
      s_[j] = ok ? src[e] : 0;
      d_[j] = ok ? dst[e] : 0;
      b_[j] = ok ? (d_[j] / SLICE) : -1;
      if (ok) lp_[j] = atomicAdd(&cntw[wv][b_[j]], 1);
    }
    __syncthreads();
    if (tid == 0) {
      int run = 0;
      for (int b = 0; b < 8; ++b) {
        bstart[b] = run;
        int t = 0;
        for (int w = 0; w < 4; ++w) { basew[w][b] = run + t; t += cntw[w][b]; }
        run += t;
        gbase[b] = atomicAdd(&pcnt[b * 16], t);
      }
      bstart[8] = run;
    }
    __syncthreads();
#pragma unroll
    for (int j = 0; j < 8; ++j)
      if (b_[j] >= 0)
        buf[basew[wv][b_[j]] + lp_[j]] = make_uint2((unsigned)s_[j], (unsigned)d_[j]);
    __syncthreads();
    int total = bstart[8];
    for (int i = tid; i < total; i += 256) {
      int b = 0;
      while (bstart[b + 1] <= i) ++b;
      int gi = gbase[b] + (i - bstart[b]);
      if (gi < PART_CAP) parts[(size_t)b * PART_CAP + gi] = buf[i];
    }
    __syncthreads();
  }
}

// ---------- phase 2: degree count over partitioned edges (slice-local) ----------
__global__ __launch_bounds__(256) void deg_part_k(const uint2* __restrict__ parts,
                                                  const int* __restrict__ pcnt,
                                                  int* __restrict__ deg) {
  int slice = blockIdx.x & 7;
  const uint2* p = parts + (size_t)slice * PART_CAP;
  int n = min(pcnt[slice * 16], PART_CAP);
  int nb = gridDim.x >> 3, bid = blockIdx.x >> 3;
  for (int i = bid * 256 + threadIdx.x; i < n; i += nb * 256)
    atomicAdd(&deg[p[i].y], 1);
}

__global__ __launch_bounds__(1024) void scan1_k(const int* __restrict__ deg,
                                                int* __restrict__ excl,
                                                int* __restrict__ bsum, int n) {
  __shared__ int lds[1024];
  int tid = threadIdx.x;
  int gid = blockIdx.x * 1024 + tid;
  int v = (gid < n) ? deg[gid] : 0;
  lds[tid] = v;
  __syncthreads();
  for (int off = 1; off < 1024; off <<= 1) {
    int t = (tid >= off) ? lds[tid - off] : 0;
    __syncthreads();
    lds[tid] += t;
    __syncthreads();
  }
  if (gid < n) excl[gid] = lds[tid] - v;
  if (tid == 1023) bsum[blockIdx.x] = lds[1023];
}

__global__ void scan2_k(int* __restrict__ bsum, int nb) {
  __shared__ int lds[128];
  int tid = threadIdx.x;
  int v = (tid < nb) ? bsum[tid] : 0;
  lds[tid] = v;
  __syncthreads();
  for (int off = 1; off < 128; off <<= 1) {
    int t = (tid >= off) ? lds[tid - off] : 0;
    __syncthreads();
    lds[tid] += t;
    __syncthreads();
  }
  if (tid < nb) bsum[tid] = lds[tid] - v;
}

__global__ __launch_bounds__(256) void scan3_k(int* __restrict__ excl,
                                               const int* __restrict__ bsum,
                                               const int* __restrict__ deg,
                                               float* __restrict__ inv, int n) {
  int gid = blockIdx.x * 256 + threadIdx.x;
  if (gid < n) {
    excl[gid] += bsum[gid >> 10];
    inv[gid] = 1.0f / fmaxf((float)deg[gid], 1.0f);
  }
}

// ---------- phase 3: CSR fill from partitioned edges (slice-local). offs -> end offsets ----------
__global__ __launch_bounds__(256) void csr_fill_k(const uint2* __restrict__ parts,
                                                  const int* __restrict__ pcnt,
                                                  int* __restrict__ cursor,
                                                  int* __restrict__ csr) {
  int slice = blockIdx.x & 7;
  const uint2* p = parts + (size_t)slice * PART_CAP;
  int n = min(pcnt[slice * 16], PART_CAP);
  int nb = gridDim.x >> 3, bid = blockIdx.x >> 3;
  for (int i = bid * 256 + threadIdx.x; i < n; i += nb * 256) {
    uint2 e = p[i];
    int pos = atomicAdd(&cursor[e.y], 1);
    csr[pos] = (int)e.x;
  }
}

// ---------- fp32 -> bf16 bulk convert ----------
__global__ __launch_bounds__(256) void tobf_k(const float* __restrict__ x,
                                              unsigned short* __restrict__ y, int n) {
  int idx = (blockIdx.x * 256 + threadIdx.x) * 4;
  if (idx < n) {
    float4 v = ld4(x + idx);
    unsigned int lo = (unsigned int)f2bf(v.x) | ((unsigned int)f2bf(v.y) << 16);
    unsigned int hi = (unsigned int)f2bf(v.z) | ((unsigned int)f2bf(v.w) << 16);
    *(uint2*)(y + idx) = make_uint2(lo, hi);
  }
}

// ---------- all weights -> bf16, one kernel ----------
__device__ inline void conv4(const float* s, unsigned short* d, int q) {
  float4 v = ld4(s + q * 4);
  unsigned int lo = (unsigned int)f2bf(v.x) | ((unsigned int)f2bf(v.y) << 16);
  unsigned int hi = (unsigned int)f2bf(v.z) | ((unsigned int)f2bf(v.w) << 16);
  ((uint2*)d)[q] = make_uint2(lo, hi);
}
__global__ __launch_bounds__(256) void wconv_k(const float* W1, const float* W2,
                                               const float* Wm1, const float* Wm2,
                                               const float* Wm3,
                                               unsigned short* W1bf, unsigned short* W2bf,
                                               unsigned short* Wm1bf, unsigned short* Wm2bf,
                                               unsigned short* Wm3bf) {
  int q = blockIdx.x * 256 + threadIdx.x;   // float4 index, 24576 total
  if (q < 4096) conv4(W1, W1bf, q);
  else if (q < 8192) conv4(W2, W2bf, q - 4096);
  else if (q < 16384) conv4(Wm1, Wm1bf, q - 8192);
  else if (q < 20480) conv4(Wm2, Wm2bf, q - 16384);
  else if (q < 24576) conv4(Wm3, Wm3bf, q - 20480);
}

// ---------- gather layer 1: agg1[v] = inv[v]*sum feat[nbrs] (bf16 in/out, fp32 accum) ----------
__global__ __launch_bounds__(256) void gather1_k(const unsigned short* __restrict__ featbf,
                                                 const int* __restrict__ csr,
                                                 const int* __restrict__ offs_end,
                                                 const int* __restrict__ degv,
                                                 const float* __restrict__ inv,
                                                 unsigned short* __restrict__ agg1) {
  int v = blockIdx.x * 8 + (threadIdx.x >> 5);
  if (v >= NN) return;
  int lane = threadIdx.x & 31;
  int cnt = degv[v];
  int start = offs_end[v] - cnt;
  const uint2* fb = (const uint2*)featbf;
  float a0 = 0.f, a1 = 0.f, a2 = 0.f, a3 = 0.f;
  int i = 0;
  for (; i + 4 <= cnt; i += 4) {
    int s0 = csr[start + i], s1 = csr[start + i + 1];
    int s2 = csr[start + i + 2], s3 = csr[start + i + 3];
    uint2 x0 = fb[(size_t)s0 * 32 + lane];
    uint2 x1 = fb[(size_t)s1 * 32 + lane];
    uint2 x2 = fb[(size_t)s2 * 32 + lane];
    uint2 x3 = fb[(size_t)s3 * 32 + lane];
    acc4(a0, a1, a2, a3, x0);
    acc4(a0, a1, a2, a3, x1);
    acc4(a0, a1, a2, a3, x2);
    acc4(a0, a1, a2, a3, x3);
  }
  for (; i < cnt; ++i) {
    uint2 x = fb[(size_t)csr[start + i] * 32 + lane];
    acc4(a0, a1, a2, a3, x);
  }
  float iv = inv[v];
  unsigned int lo = (unsigned int)f2bf(a0 * iv) | ((unsigned int)f2bf(a1 * iv) << 16);
  unsigned int hi = (unsigned int)f2bf(a2 * iv) | ((unsigned int)f2bf(a3 * iv) << 16);
  ((uint2*)agg1)[(size_t)v * 32 + lane] = make_uint2(lo, hi);
}

// ---------- gather layer 2 at masked nodes + bf16 concat ----------
__global__ __launch_bounds__(256) void gather2_k(const unsigned short* __restrict__ h1bf,
                                                 const unsigned short* __restrict__ featbf,
                                                 const int* __restrict__ masked,
                                                 const int* __restrict__ csr,
                                                 const int* __restrict__ offs_end,
                                                 const int* __restrict__ degv,
                                                 const float* __restrict__ inv,
                                                 unsigned short* __restrict__ agg2bf,
                                                 unsigned short* __restrict__ xcatbf) {
  int m = blockIdx.x * 8 + (threadIdx.x >> 5);
  if (m >= NM) return;
  int lane = threadIdx.x & 31;
  int v = masked[m];
  int cnt = degv[v];
  int start = offs_end[v] - cnt;
  const uint2* fb = (const uint2*)h1bf;
  float a0 = 0.f, a1 = 0.f, a2 = 0.f, a3 = 0.f;
  int i = 0;
  for (; i + 4 <= cnt; i += 4) {
    int s0 = csr[start + i], s1 = csr[start + i + 1];
    int s2 = csr[start + i + 2], s3 = csr[start + i + 3];
    uint2 x0 = fb[(size_t)s0 * 32 + lane];
    uint2 x1 = fb[(size_t)s1 * 32 + lane];
    uint2 x2 = fb[(size_t)s2 * 32 + lane];
    uint2 x3 = fb[(size_t)s3 * 32 + lane];
    acc4(a0, a1, a2, a3, x0);
    acc4(a0, a1, a2, a3, x1);
    acc4(a0, a1, a2, a3, x2);
    acc4(a0, a1, a2, a3, x3);
  }
  for (; i < cnt; ++i) {
    uint2 x = fb[(size_t)csr[start + i] * 32 + lane];
    acc4(a0, a1, a2, a3, x);
  }
  float iv = inv[v];
  unsigned int lo = (unsigned int)f2bf(a0 * iv) | ((unsigned int)f2bf(a1 * iv) << 16);
  unsigned int hi = (unsigned int)f2bf(a2 * iv) | ((unsigned int)f2bf(a3 * iv) << 16);
  ((uint2*)agg2bf)[(size_t)m * 32 + lane] = make_uint2(lo, hi);
  ((uint2*)xcatbf)[(size_t)m * 64 + 32 + lane] = ((const uint2*)featbf)[(size_t)v * 32 + lane];
}

// ---------- generic bf16 MFMA GEMM: Y = post(A[n][KT*32] @ W[KT*32][128]) ----------
template<int KT, bool BIAS, bool RELU, bool F32OUT>
__global__ __launch_bounds__(256) void mfma_gemm_k(const unsigned short* __restrict__ Abf,
                                                   const unsigned short* __restrict__ Wbf,
                                                   const float* __restrict__ bias,
                                                   void* __restrict__ Yout,
                                                   int ldy, int nrows) {
  const int lda = KT * 32;
  const int tid = threadIdx.x;
  const int wave = tid >> 6;      // col-tiles wave, wave+4
  const int lane = tid & 63;
  const int l15 = lane & 15;
  const int l4 = lane >> 4;
  const int rbase = blockIdx.x * 64;

  bf16x8 Bfr[2][KT];
#pragma unroll
  for (int c = 0; c < 2; ++c) {
    int col = (wave + 4 * c) * 16 + l15;
#pragma unroll
    for (int kt = 0; kt < KT; ++kt) {
      bf16x8 b;
#pragma unroll
      for (int i = 0; i < 8; ++i)
        b[i] = (short)Wbf[(kt * 32 + l4 * 8 + i) * 128 + col];
      Bfr[c][kt] = b;
    }
  }
  float bias0 = 0.f, bias1 = 0.f;
  if (BIAS) { bias0 = bias[wave * 16 + l15]; bias1 = bias[(wave + 4) * 16 + l15]; }

  for (int rsub = 0; rsub < 4; ++rsub) {
    int arow = rbase + rsub * 16 + l15;
    const unsigned short* ap = Abf + (size_t)(arow < nrows ? arow : 0) * lda;
    f32x4 acc0 = {0.f, 0.f, 0.f, 0.f};
    f32x4 acc1 = {0.f, 0.f, 0.f, 0.f};
#pragma unroll
    for (int kt = 0; kt < KT; ++kt) {
      bf16x8 a = *(const bf16x8*)(ap + kt * 32 + l4 * 8);
      acc0 = __builtin_amdgcn_mfma_f32_16x16x32_bf16(a, Bfr[0][kt], acc0, 0, 0, 0);
      acc1 = __builtin_amdgcn_mfma_f32_16x16x32_bf16(a, Bfr[1][kt], acc1, 0, 0, 0);
    }
#pragma unroll
    for (int r = 0; r < 4; ++r) {
      int orow = rbase + rsub * 16 + l4 * 4 + r;
      if (orow < nrows) {
        float v0 = acc0[r] + bias0, v1 = acc1[r] + bias1;
        if (RELU) { v0 = fmaxf(v0, 0.f); v1 = fmaxf(v1, 0.f); }
        if (F32OUT) {
          ((float*)Yout)[(size_t)orow * ldy + wave * 16 + l15] = v0;
          ((float*)Yout)[(size_t)orow * ldy + (wave + 4) * 16 + l15] = v1;
        } else {
          ((unsigned short*)Yout)[(size_t)orow * ldy + wave * 16 + l15] = f2bf(v0);
          ((unsigned short*)Yout)[(size_t)orow * ldy + (wave + 4) * 16 + l15] = f2bf(v1);
        }
      }
    }
  }
}

extern "C" void kernel_launch(void* const* d_in, const int* in_sizes, int n_in,
                              void* d_out, int out_size, void* d_ws, size_t ws_size,
                              hipStream_t stream) {
  const float* feat = (const float*)d_in[0];
  const int* src = (const int*)d_in[1];
  const int* dst = (const int*)d_in[2];
  const int* masked = (const int*)d_in[3];
  const float* W1 = (const float*)d_in[4];
  const float* b1 = (const float*)d_in[5];
  const float* W2 = (const float*)d_in[6];
  const float* b2 = (const float*)d_in[7];
  const float* Wm1 = (const float*)d_in[8];
  const float* bm1 = (const float*)d_in[9];
  const float* Wm2 = (const float*)d_in[10];
  const float* bm2 = (const float*)d_in[11];
  const float* Wm3 = (const float*)d_in[12];
  float* out = (float*)d_out;

  // ---- workspace layout ----
  char* p = (char*)d_ws;
  int* deg = (int*)p;              p += (size_t)NN * 4;
  int* offs = (int*)p;             p += (size_t)NN * 4;
  int* bsum = (int*)p;             p += 128 * 4;
  int* pcnt = (int*)p;             p += 128 * 4;
  float* inv = (float*)p;          p += (size_t)NN * 4;
  int* csr = (int*)p;              p += (size_t)NE * 4;
  p = (char*)(((size_t)p + 15) & ~(size_t)15);
  unsigned short* featbf = (unsigned short*)p;  p += (size_t)NN * 128 * 2;
  unsigned short* agg1 = (unsigned short*)p;    p += (size_t)NN * 128 * 2;
  unsigned short* h1bf = (unsigned short*)p;    p += (size_t)NN * 128 * 2;
  unsigned short* W1bf = (unsigned short*)p;    p += 16384 * 2;
  unsigned short* W2bf = (unsigned short*)p;    p += 16384 * 2;
  unsigned short* Wm1bf = (unsigned short*)p;   p += 32768 * 2;
  unsigned short* Wm2bf = (unsigned short*)p;   p += 16384 * 2;
  unsigned short* Wm3bf = (unsigned short*)p;   p += 16384 * 2;
  p = (char*)(((size_t)p + 15) & ~(size_t)15);
  uint2* parts = (uint2*)p;                     // 8*PART_CAP*8B = 13.8MB, dead after csr_fill
  unsigned short* agg2bf = (unsigned short*)p;  // aliases over parts (written after fill)
  unsigned short* xcatbf = agg2bf + (size_t)NM * 128;
  unsigned short* y1bf = xcatbf + (size_t)NM * 256;
  unsigned short* y2bf = y1bf + (size_t)NM * 128;

  (void)hipMemsetAsync(deg, 0, (size_t)NN * 4, stream);
  (void)hipMemsetAsync(pcnt, 0, 128 * 4, stream);

  // sparse build
  partition_k<<<(NE + 4 * PCHUNK - 1) / (4 * PCHUNK), 256, 0, stream>>>(src, dst, parts, pcnt);
  deg_part_k<<<512, 256, 0, stream>>>(parts, pcnt, deg);
  int nb = (NN + 1023) / 1024;
  scan1_k<<<nb, 1024, 0, stream>>>(deg, offs, bsum, NN);
  scan2_k<<<1, 128, 0, stream>>>(bsum, nb);
  scan3_k<<<(NN + 255) / 256, 256, 0, stream>>>(offs, bsum, deg, inv, NN);
  csr_fill_k<<<512, 256, 0, stream>>>(parts, pcnt, offs, csr);   // offs -> end offsets

  // bf16 conversions
  tobf_k<<<(NN * 128 / 4 + 255) / 256, 256, 0, stream>>>(feat, featbf, NN * 128);
  wconv_k<<<96, 256, 0, stream>>>(W1, W2, Wm1, Wm2, Wm3, W1bf, W2bf, Wm1bf, Wm2bf, Wm3bf);

  // GCN layer 1: agg1 = inv*agg(featbf);  h1 = relu(agg1 @ W1 + b1)
  gather1_k<<<(NN + 7) / 8, 256, 0, stream>>>(featbf, csr, offs, deg, inv, agg1);
  mfma_gemm_k<4, true, true, false><<<(NN + 63) / 64, 256, 0, stream>>>(agg1, W1bf, b1, h1bf, 128, NN);

  // GCN layer 2 at masked nodes + concat
  gather2_k<<<(NM + 7) / 8, 256, 0, stream>>>(h1bf, featbf, masked, csr, offs, deg, inv, agg2bf, xcatbf);
  int gm = (NM + 63) / 64;
  mfma_gemm_k<4, true, true, false><<<gm, 256, 0, stream>>>(agg2bf, W2bf, b2, xcatbf, 256, NM);

  // MLP head (bf16 MFMA)
  mfma_gemm_k<8, true, true, false><<<gm, 256, 0, stream>>>(xcatbf, Wm1bf, bm1, y1bf, 128, NM);
  mfma_gemm_k<4, true, true, false><<<gm, 256, 0, stream>>>(y1bf, Wm2bf, bm2, y2bf, 128, NM);
  mfma_gemm_k<4, false, false, true><<<gm, 256, 0, stream>>>(y2bf, Wm3bf, nullptr, out, 128, NM);
}

// Round 6
// 193.658 us; speedup vs baseline: 2.7781x; 1.6952x over previous
//
#include <hip/hip_runtime.h>

#define NN 100000
#define NE 1600000
#define NM 10000
#define NSB 256
#define SUBN 391          // nodes per sub-bucket; 256*391 = 100096 >= NN
#define CAP2 7424         // per-sub-bucket edge capacity (mean 6251, sigma 79)
#define PCH 2048

typedef __attribute__((ext_vector_type(8))) short bf16x8;
typedef __attribute__((ext_vector_type(4))) float f32x4;

__device__ inline float4 ld4(const float* p) { return *(const float4*)p; }
__device__ inline float bf2f(unsigned short u) {
  union { unsigned int i; float f; } c; c.i = ((unsigned int)u) << 16; return c.f;
}
__device__ inline unsigned short f2bf(float f) {
  union { float f; unsigned int i; } c; c.f = f;
  unsigned int u = c.i + 0x7fffu + ((c.i >> 16) & 1u);
  return (unsigned short)(u >> 16);
}
__device__ inline void acc4(float& a0, float& a1, float& a2, float& a3, uint2 u) {
  a0 += bf2f((unsigned short)(u.x));
  a1 += bf2f((unsigned short)(u.x >> 16));
  a2 += bf2f((unsigned short)(u.y));
  a3 += bf2f((unsigned short)(u.y >> 16));
}

// ---------- 256-way edge partition, coalesced appends ----------
__global__ __launch_bounds__(256) void part2_k(const int* __restrict__ src,
                                               const int* __restrict__ dst,
                                               unsigned* __restrict__ parts2,
                                               int* __restrict__ pcnt2) {
  __shared__ int cntw[4][NSB];
  __shared__ int basew[4][NSB];
  __shared__ int bstart[NSB + 1];
  __shared__ int gbase[NSB];
  __shared__ int scn[NSB];
  __shared__ unsigned buf[PCH];
  const int tid = threadIdx.x;
  const int wv = tid >> 6;
  const int e0 = blockIdx.x * PCH;

  for (int i = tid; i < 4 * NSB; i += 256) ((int*)cntw)[i] = 0;
  __syncthreads();

  unsigned pk[8];
  int b_[8], lp_[8];
#pragma unroll
  for (int j = 0; j < 8; ++j) {
    int e = e0 + j * 256 + tid;
    bool ok = e < NE;
    int s = ok ? src[e] : 0;
    int d = ok ? dst[e] : 0;
    int b = d / SUBN;
    int ld = d - b * SUBN;
    pk[j] = ((unsigned)ld << 17) | (unsigned)s;
    b_[j] = ok ? b : -1;
    if (ok) lp_[j] = atomicAdd(&cntw[wv][b], 1);
  }
  __syncthreads();
  int t0 = cntw[0][tid], t1 = cntw[1][tid], t2 = cntw[2][tid], t3 = cntw[3][tid];
  int tot = t0 + t1 + t2 + t3;
  scn[tid] = tot;
  __syncthreads();
  for (int off = 1; off < NSB; off <<= 1) {
    int t = (tid >= off) ? scn[tid - off] : 0;
    __syncthreads();
    scn[tid] += t;
    __syncthreads();
  }
  int excl = scn[tid] - tot;
  bstart[tid] = excl;
  basew[0][tid] = excl;
  basew[1][tid] = excl + t0;
  basew[2][tid] = excl + t0 + t1;
  basew[3][tid] = excl + t0 + t1 + t2;
  gbase[tid] = atomicAdd(&pcnt2[tid], tot);
  if (tid == NSB - 1) bstart[NSB] = scn[NSB - 1];
  __syncthreads();
#pragma unroll
  for (int j = 0; j < 8; ++j)
    if (b_[j] >= 0) buf[basew[wv][b_[j]] + lp_[j]] = pk[j];
  __syncthreads();
  int total = bstart[NSB];
  for (int i = tid; i < total; i += 256) {
    int lo = 0, hi = NSB;
    while (hi - lo > 1) { int mid = (lo + hi) >> 1; if (bstart[mid] <= i) lo = mid; else hi = mid; }
    int gi = gbase[lo] + (i - bstart[lo]);
    if (gi < CAP2) parts2[(size_t)lo * CAP2 + gi] = buf[i];
  }
}

// ---------- per-sub-bucket degree histogram, coalesced deg writes ----------
__global__ __launch_bounds__(256) void deg2_k(const unsigned* __restrict__ parts2,
                                              const int* __restrict__ pcnt2,
                                              int* __restrict__ deg) {
  __shared__ int cnt[SUBN];
  int sb = blockIdx.x;
  int n = min(pcnt2[sb], CAP2);
  const unsigned* p = parts2 + (size_t)sb * CAP2;
  for (int i = threadIdx.x; i < SUBN; i += 256) cnt[i] = 0;
  __syncthreads();
  for (int i = threadIdx.x; i < n; i += 256) atomicAdd(&cnt[p[i] >> 17], 1);
  __syncthreads();
  int base = sb * SUBN;
  for (int i = threadIdx.x; i < SUBN; i += 256)
    if (base + i < NN) deg[base + i] = cnt[i];
}

__global__ __launch_bounds__(1024) void scan1_k(const int* __restrict__ deg,
                                                int* __restrict__ excl,
                                                int* __restrict__ bsum, int n) {
  __shared__ int lds[1024];
  int tid = threadIdx.x;
  int gid = blockIdx.x * 1024 + tid;
  int v = (gid < n) ? deg[gid] : 0;
  lds[tid] = v;
  __syncthreads();
  for (int off = 1; off < 1024; off <<= 1) {
    int t = (tid >= off) ? lds[tid - off] : 0;
    __syncthreads();
    lds[tid] += t;
    __syncthreads();
  }
  if (gid < n) excl[gid] = lds[tid] - v;
  if (tid == 1023) bsum[blockIdx.x] = lds[1023];
}

__global__ void scan2_k(int* __restrict__ bsum, int nb) {
  __shared__ int lds[128];
  int tid = threadIdx.x;
  int v = (tid < nb) ? bsum[tid] : 0;
  lds[tid] = v;
  __syncthreads();
  for (int off = 1; off < 128; off <<= 1) {
    int t = (tid >= off) ? lds[tid - off] : 0;
    __syncthreads();
    lds[tid] += t;
    __syncthreads();
  }
  if (tid < nb) bsum[tid] = lds[tid] - v;
}

// finalize: offs -> END offsets per node; inv = 1/max(deg,1)
__global__ __launch_bounds__(256) void scan3_k(int* __restrict__ excl,
                                               const int* __restrict__ bsum,
                                               const int* __restrict__ deg,
                                               float* __restrict__ inv, int n) {
  int gid = blockIdx.x * 256 + threadIdx.x;
  if (gid < n) {
    excl[gid] += bsum[gid >> 10] + deg[gid];
    inv[gid] = 1.0f / fmaxf((float)deg[gid], 1.0f);
  }
}

// ---------- per-sub-bucket LDS counting sort -> coalesced csr segment write ----------
__global__ __launch_bounds__(256) void sort_emit_k(const unsigned* __restrict__ parts2,
                                                   const int* __restrict__ pcnt2,
                                                   const int* __restrict__ offs_end,
                                                   const int* __restrict__ degv,
                                                   int* __restrict__ csr) {
  __shared__ int cur[SUBN];
  __shared__ int sorted[CAP2];
  int sb = blockIdx.x;
  int n = min(pcnt2[sb], CAP2);
  const unsigned* p = parts2 + (size_t)sb * CAP2;
  int base = sb * SUBN;
  int segbase = offs_end[base] - degv[base];   // start offset of first node in range
  for (int i = threadIdx.x; i < SUBN; i += 256) {
    int nd = base + i;
    cur[i] = (nd < NN) ? (offs_end[nd] - degv[nd]) : 0;
  }
  __syncthreads();
  for (int i = threadIdx.x; i < n; i += 256) {
    unsigned v = p[i];
    int pos = atomicAdd(&cur[v >> 17], 1);
    sorted[pos - segbase] = (int)(v & 0x1FFFFu);
  }
  __syncthreads();
  for (int i = threadIdx.x; i < n; i += 256) csr[segbase + i] = sorted[i];
}

// ---------- fp32 -> bf16 bulk convert ----------
__global__ __launch_bounds__(256) void tobf_k(const float* __restrict__ x,
                                              unsigned short* __restrict__ y, int n) {
  int idx = (blockIdx.x * 256 + threadIdx.x) * 4;
  if (idx < n) {
    float4 v = ld4(x + idx);
    unsigned int lo = (unsigned int)f2bf(v.x) | ((unsigned int)f2bf(v.y) << 16);
    unsigned int hi = (unsigned int)f2bf(v.z) | ((unsigned int)f2bf(v.w) << 16);
    *(uint2*)(y + idx) = make_uint2(lo, hi);
  }
}

__device__ inline void conv4(const float* s, unsigned short* d, int q) {
  float4 v = ld4(s + q * 4);
  unsigned int lo = (unsigned int)f2bf(v.x) | ((unsigned int)f2bf(v.y) << 16);
  unsigned int hi = (unsigned int)f2bf(v.z) | ((unsigned int)f2bf(v.w) << 16);
  ((uint2*)d)[q] = make_uint2(lo, hi);
}
__global__ __launch_bounds__(256) void wconv_k(const float* W1, const float* W2,
                                               const float* Wm1, const float* Wm2,
                                               const float* Wm3,
                                               unsigned short* W1bf, unsigned short* W2bf,
                                               unsigned short* Wm1bf, unsigned short* Wm2bf,
                                               unsigned short* Wm3bf) {
  int q = blockIdx.x * 256 + threadIdx.x;
  if (q < 4096) conv4(W1, W1bf, q);
  else if (q < 8192) conv4(W2, W2bf, q - 4096);
  else if (q < 16384) conv4(Wm1, Wm1bf, q - 8192);
  else if (q < 20480) conv4(Wm2, Wm2bf, q - 16384);
  else if (q < 24576) conv4(Wm3, Wm3bf, q - 20480);
}

// ---------- gather layer 1 ----------
__global__ __launch_bounds__(256) void gather1_k(const unsigned short* __restrict__ featbf,
                                                 const int* __restrict__ csr,
                                                 const int* __restrict__ offs_end,
                                                 const int* __restrict__ degv,
                                                 const float* __restrict__ inv,
                                                 unsigned short* __restrict__ agg1) {
  int v = blockIdx.x * 8 + (threadIdx.x >> 5);
  if (v >= NN) return;
  int lane = threadIdx.x & 31;
  int cnt = degv[v];
  int start = offs_end[v] - cnt;
  const uint2* fb = (const uint2*)featbf;
  float a0 = 0.f, a1 = 0.f, a2 = 0.f, a3 = 0.f;
  int i = 0;
  for (; i + 4 <= cnt; i += 4) {
    int s0 = csr[start + i], s1 = csr[start + i + 1];
    int s2 = csr[start + i + 2], s3 = csr[start + i + 3];
    uint2 x0 = fb[(size_t)s0 * 32 + lane];
    uint2 x1 = fb[(size_t)s1 * 32 + lane];
    uint2 x2 = fb[(size_t)s2 * 32 + lane];
    uint2 x3 = fb[(size_t)s3 * 32 + lane];
    acc4(a0, a1, a2, a3, x0);
    acc4(a0, a1, a2, a3, x1);
    acc4(a0, a1, a2, a3, x2);
    acc4(a0, a1, a2, a3, x3);
  }
  for (; i < cnt; ++i) {
    uint2 x = fb[(size_t)csr[start + i] * 32 + lane];
    acc4(a0, a1, a2, a3, x);
  }
  float iv = inv[v];
  unsigned int lo = (unsigned int)f2bf(a0 * iv) | ((unsigned int)f2bf(a1 * iv) << 16);
  unsigned int hi = (unsigned int)f2bf(a2 * iv) | ((unsigned int)f2bf(a3 * iv) << 16);
  ((uint2*)agg1)[(size_t)v * 32 + lane] = make_uint2(lo, hi);
}

// ---------- gather layer 2 at masked nodes + bf16 concat ----------
__global__ __launch_bounds__(256) void gather2_k(const unsigned short* __restrict__ h1bf,
                                                 const unsigned short* __restrict__ featbf,
                                                 const int* __restrict__ masked,
                                                 const int* __restrict__ csr,
                                                 const int* __restrict__ offs_end,
                                                 const int* __restrict__ degv,
                                                 const float* __restrict__ inv,
                                                 unsigned short* __restrict__ agg2bf,
                                                 unsigned short* __restrict__ xcatbf) {
  int m = blockIdx.x * 8 + (threadIdx.x >> 5);
  if (m >= NM) return;
  int lane = threadIdx.x & 31;
  int v = masked[m];
  int cnt = degv[v];
  int start = offs_end[v] - cnt;
  const uint2* fb = (const uint2*)h1bf;
  float a0 = 0.f, a1 = 0.f, a2 = 0.f, a3 = 0.f;
  int i = 0;
  for (; i + 4 <= cnt; i += 4) {
    int s0 = csr[start + i], s1 = csr[start + i + 1];
    int s2 = csr[start + i + 2], s3 = csr[start + i + 3];
    uint2 x0 = fb[(size_t)s0 * 32 + lane];
    uint2 x1 = fb[(size_t)s1 * 32 + lane];
    uint2 x2 = fb[(size_t)s2 * 32 + lane];
    uint2 x3 = fb[(size_t)s3 * 32 + lane];
    acc4(a0, a1, a2, a3, x0);
    acc4(a0, a1, a2, a3, x1);
    acc4(a0, a1, a2, a3, x2);
    acc4(a0, a1, a2, a3, x3);
  }
  for (; i < cnt; ++i) {
    uint2 x = fb[(size_t)csr[start + i] * 32 + lane];
    acc4(a0, a1, a2, a3, x);
  }
  float iv = inv[v];
  unsigned int lo = (unsigned int)f2bf(a0 * iv) | ((unsigned int)f2bf(a1 * iv) << 16);
  unsigned int hi = (unsigned int)f2bf(a2 * iv) | ((unsigned int)f2bf(a3 * iv) << 16);
  ((uint2*)agg2bf)[(size_t)m * 32 + lane] = make_uint2(lo, hi);
  ((uint2*)xcatbf)[(size_t)m * 64 + 32 + lane] = ((const uint2*)featbf)[(size_t)v * 32 + lane];
}

// ---------- generic bf16 MFMA GEMM ----------
template<int KT, bool BIAS, bool RELU, bool F32OUT>
__global__ __launch_bounds__(256) void mfma_gemm_k(const unsigned short* __restrict__ Abf,
                                                   const unsigned short* __restrict__ Wbf,
                                                   const float* __restrict__ bias,
                                                   void* __restrict__ Yout,
                                                   int ldy, int nrows) {
  const int lda = KT * 32;
  const int tid = threadIdx.x;
  const int wave = tid >> 6;
  const int lane = tid & 63;
  const int l15 = lane & 15;
  const int l4 = lane >> 4;
  const int rbase = blockIdx.x * 64;

  bf16x8 Bfr[2][KT];
#pragma unroll
  for (int c = 0; c < 2; ++c) {
    int col = (wave + 4 * c) * 16 + l15;
#pragma unroll
    for (int kt = 0; kt < KT; ++kt) {
      bf16x8 b;
#pragma unroll
      for (int i = 0; i < 8; ++i)
        b[i] = (short)Wbf[(kt * 32 + l4 * 8 + i) * 128 + col];
      Bfr[c][kt] = b;
    }
  }
  float bias0 = 0.f, bias1 = 0.f;
  if (BIAS) { bias0 = bias[wave * 16 + l15]; bias1 = bias[(wave + 4) * 16 + l15]; }

  for (int rsub = 0; rsub < 4; ++rsub) {
    int arow = rbase + rsub * 16 + l15;
    const unsigned short* ap = Abf + (size_t)(arow < nrows ? arow : 0) * lda;
    f32x4 acc0 = {0.f, 0.f, 0.f, 0.f};
    f32x4 acc1 = {0.f, 0.f, 0.f, 0.f};
#pragma unroll
    for (int kt = 0; kt < KT; ++kt) {
      bf16x8 a = *(const bf16x8*)(ap + kt * 32 + l4 * 8);
      acc0 = __builtin_amdgcn_mfma_f32_16x16x32_bf16(a, Bfr[0][kt], acc0, 0, 0, 0);
      acc1 = __builtin_amdgcn_mfma_f32_16x16x32_bf16(a, Bfr[1][kt], acc1, 0, 0, 0);
    }
#pragma unroll
    for (int r = 0; r < 4; ++r) {
      int orow = rbase + rsub * 16 + l4 * 4 + r;
      if (orow < nrows) {
        float v0 = acc0[r] + bias0, v1 = acc1[r] + bias1;
        if (RELU) { v0 = fmaxf(v0, 0.f); v1 = fmaxf(v1, 0.f); }
        if (F32OUT) {
          ((float*)Yout)[(size_t)orow * ldy + wave * 16 + l15] = v0;
          ((float*)Yout)[(size_t)orow * ldy + (wave + 4) * 16 + l15] = v1;
        } else {
          ((unsigned short*)Yout)[(size_t)orow * ldy + wave * 16 + l15] = f2bf(v0);
          ((unsigned short*)Yout)[(size_t)orow * ldy + (wave + 4) * 16 + l15] = f2bf(v1);
        }
      }
    }
  }
}

extern "C" void kernel_launch(void* const* d_in, const int* in_sizes, int n_in,
                              void* d_out, int out_size, void* d_ws, size_t ws_size,
                              hipStream_t stream) {
  const float* feat = (const float*)d_in[0];
  const int* src = (const int*)d_in[1];
  const int* dst = (const int*)d_in[2];
  const int* masked = (const int*)d_in[3];
  const float* W1 = (const float*)d_in[4];
  const float* b1 = (const float*)d_in[5];
  const float* W2 = (const float*)d_in[6];
  const float* b2 = (const float*)d_in[7];
  const float* Wm1 = (const float*)d_in[8];
  const float* bm1 = (const float*)d_in[9];
  const float* Wm2 = (const float*)d_in[10];
  const float* bm2 = (const float*)d_in[11];
  const float* Wm3 = (const float*)d_in[12];
  float* out = (float*)d_out;

  // ---- workspace layout ----
  char* p = (char*)d_ws;
  int* deg = (int*)p;              p += (size_t)NN * 4;
  int* offs = (int*)p;             p += (size_t)NN * 4;
  int* bsum = (int*)p;             p += 128 * 4;
  int* pcnt2 = (int*)p;            p += NSB * 4;
  float* inv = (float*)p;          p += (size_t)NN * 4;
  int* csr = (int*)p;              p += (size_t)NE * 4;
  p = (char*)(((size_t)p + 15) & ~(size_t)15);
  unsigned* parts2 = (unsigned*)p; p += (size_t)NSB * CAP2 * 4;   // 7.6 MB
  p = (char*)(((size_t)p + 15) & ~(size_t)15);
  unsigned short* featbf = (unsigned short*)p;  p += (size_t)NN * 128 * 2;
  unsigned short* agg1 = (unsigned short*)p;    p += (size_t)NN * 128 * 2;
  unsigned short* h1bf = (unsigned short*)p;    p += (size_t)NN * 128 * 2;
  unsigned short* W1bf = (unsigned short*)p;    p += 16384 * 2;
  unsigned short* W2bf = (unsigned short*)p;    p += 16384 * 2;
  unsigned short* Wm1bf = (unsigned short*)p;   p += 32768 * 2;
  unsigned short* Wm2bf = (unsigned short*)p;   p += 16384 * 2;
  unsigned short* Wm3bf = (unsigned short*)p;   p += 16384 * 2;
  p = (char*)(((size_t)p + 15) & ~(size_t)15);
  unsigned short* agg2bf = (unsigned short*)p;  p += (size_t)NM * 128 * 2;
  unsigned short* xcatbf = (unsigned short*)p;  p += (size_t)NM * 256 * 2;
  unsigned short* y1bf = (unsigned short*)p;    p += (size_t)NM * 128 * 2;
  unsigned short* y2bf = (unsigned short*)p;    p += (size_t)NM * 128 * 2;

  (void)hipMemsetAsync(pcnt2, 0, NSB * 4, stream);

  // sparse build: 256-way partition -> histogram -> scan -> LDS counting sort
  part2_k<<<(NE + PCH - 1) / PCH, 256, 0, stream>>>(src, dst, parts2, pcnt2);
  deg2_k<<<NSB, 256, 0, stream>>>(parts2, pcnt2, deg);
  int nb = (NN + 1023) / 1024;
  scan1_k<<<nb, 1024, 0, stream>>>(deg, offs, bsum, NN);
  scan2_k<<<1, 128, 0, stream>>>(bsum, nb);
  scan3_k<<<(NN + 255) / 256, 256, 0, stream>>>(offs, bsum, deg, inv, NN);
  sort_emit_k<<<NSB, 256, 0, stream>>>(parts2, pcnt2, offs, deg, csr);

  // bf16 conversions
  tobf_k<<<(NN * 128 / 4 + 255) / 256, 256, 0, stream>>>(feat, featbf, NN * 128);
  wconv_k<<<96, 256, 0, stream>>>(W1, W2, Wm1, Wm2, Wm3, W1bf, W2bf, Wm1bf, Wm2bf, Wm3bf);

  // GCN layer 1
  gather1_k<<<(NN + 7) / 8, 256, 0, stream>>>(featbf, csr, offs, deg, inv, agg1);
  mfma_gemm_k<4, true, true, false><<<(NN + 63) / 64, 256, 0, stream>>>(agg1, W1bf, b1, h1bf, 128, NN);

  // GCN layer 2 at masked nodes + concat
  gather2_k<<<(NM + 7) / 8, 256, 0, stream>>>(h1bf, featbf, masked, csr, offs, deg, inv, agg2bf, xcatbf);
  int gm = (NM + 63) / 64;
  mfma_gemm_k<4, true, true, false><<<gm, 256, 0, stream>>>(agg2bf, W2bf, b2, xcatbf, 256, NM);

  // MLP head (bf16 MFMA)
  mfma_gemm_k<8, true, true, false><<<gm, 256, 0, stream>>>(xcatbf, Wm1bf, bm1, y1bf, 128, NM);
  mfma_gemm_k<4, true, true, false><<<gm, 256, 0, stream>>>(y1bf, Wm2bf, bm2, y2bf, 128, NM);
  mfma_gemm_k<4, false, false, true><<<gm, 256, 0, stream>>>(y2bf, Wm3bf, nullptr, out, 128, NM);
}

// Round 7
// 181.430 us; speedup vs baseline: 2.9653x; 1.0674x over previous
//
#include <hip/hip_runtime.h>

#define NN 100000
#define NE 1600000
#define NM 10000
#define NSB 256
#define SUBN 391          // nodes per sub-bucket; 256*391 = 100096 >= NN
#define CAP2 7424         // per-sub-bucket edge capacity (mean 6251, sigma 79)
#define PCH 2048

typedef __attribute__((ext_vector_type(8))) short bf16x8;
typedef __attribute__((ext_vector_type(4))) float f32x4;

__device__ inline float4 ld4(const float* p) { return *(const float4*)p; }
__device__ inline float bf2f(unsigned short u) {
  union { unsigned int i; float f; } c; c.i = ((unsigned int)u) << 16; return c.f;
}
__device__ inline unsigned short f2bf(float f) {
  union { float f; unsigned int i; } c; c.f = f;
  unsigned int u = c.i + 0x7fffu + ((c.i >> 16) & 1u);
  return (unsigned short)(u >> 16);
}

// ---------- 256-way edge partition, coalesced appends ----------
__global__ __launch_bounds__(256) void part2_k(const int* __restrict__ src,
                                               const int* __restrict__ dst,
                                               unsigned* __restrict__ parts2,
                                               int* __restrict__ pcnt2) {
  __shared__ int cntw[4][NSB];
  __shared__ int basew[4][NSB];
  __shared__ int bstart[NSB + 1];
  __shared__ int gbase[NSB];
  __shared__ int wsum[4];
  __shared__ unsigned buf[PCH];
  const int tid = threadIdx.x;
  const int wv = tid >> 6;
  const int e0 = blockIdx.x * PCH;

  for (int i = tid; i < 4 * NSB; i += 256) ((int*)cntw)[i] = 0;
  __syncthreads();

  unsigned pk[8];
  int b_[8], lp_[8];
#pragma unroll
  for (int j = 0; j < 8; ++j) {
    int e = e0 + j * 256 + tid;
    bool ok = e < NE;
    int s = ok ? src[e] : 0;
    int d = ok ? dst[e] : 0;
    int b = d / SUBN;
    int ld = d - b * SUBN;
    pk[j] = ((unsigned)ld << 17) | (unsigned)s;
    b_[j] = ok ? b : -1;
    if (ok) lp_[j] = atomicAdd(&cntw[wv][b], 1);
  }
  __syncthreads();
  int t0 = cntw[0][tid], t1 = cntw[1][tid], t2 = cntw[2][tid], t3 = cntw[3][tid];
  int tot = t0 + t1 + t2 + t3;
  // wave-level inclusive scan of tot across 256 threads (4 waves)
  int x = tot;
#pragma unroll
  for (int d = 1; d < 64; d <<= 1) {
    int y = __shfl_up(x, d, 64);
    if ((tid & 63) >= d) x += y;
  }
  if ((tid & 63) == 63) wsum[wv] = x;
  __syncthreads();
  int woff = 0;
#pragma unroll
  for (int w = 0; w < 4; ++w) woff += (w < wv) ? wsum[w] : 0;
  int excl = x + woff - tot;
  bstart[tid] = excl;
  basew[0][tid] = excl;
  basew[1][tid] = excl + t0;
  basew[2][tid] = excl + t0 + t1;
  basew[3][tid] = excl + t0 + t1 + t2;
  gbase[tid] = atomicAdd(&pcnt2[tid], tot);
  if (tid == NSB - 1) bstart[NSB] = excl + tot;
  __syncthreads();
#pragma unroll
  for (int j = 0; j < 8; ++j)
    if (b_[j] >= 0) buf[basew[wv][b_[j]] + lp_[j]] = pk[j];
  __syncthreads();
  int total = bstart[NSB];
  for (int i = tid; i < total; i += 256) {
    int lo = 0, hi = NSB;
    while (hi - lo > 1) { int mid = (lo + hi) >> 1; if (bstart[mid] <= i) lo = mid; else hi = mid; }
    int gi = gbase[lo] + (i - bstart[lo]);
    if (gi < CAP2) parts2[(size_t)lo * CAP2 + gi] = buf[i];
  }
}

// ---------- per-sub-bucket degree histogram, coalesced deg writes ----------
__global__ __launch_bounds__(1024) void deg2_k(const unsigned* __restrict__ parts2,
                                               const int* __restrict__ pcnt2,
                                               int* __restrict__ deg) {
  __shared__ int cnt[SUBN];
  int sb = blockIdx.x;
  int n = min(pcnt2[sb], CAP2);
  const unsigned* p = parts2 + (size_t)sb * CAP2;
  for (int i = threadIdx.x; i < SUBN; i += 1024) cnt[i] = 0;
  __syncthreads();
  for (int i = threadIdx.x; i < n; i += 1024) atomicAdd(&cnt[p[i] >> 17], 1);
  __syncthreads();
  int base = sb * SUBN;
  for (int i = threadIdx.x; i < SUBN; i += 1024)
    if (base + i < NN) deg[base + i] = cnt[i];
}

__global__ __launch_bounds__(1024) void scan1_k(const int* __restrict__ deg,
                                                int* __restrict__ excl,
                                                int* __restrict__ bsum, int n) {
  __shared__ int lds[1024];
  int tid = threadIdx.x;
  int gid = blockIdx.x * 1024 + tid;
  int v = (gid < n) ? deg[gid] : 0;
  lds[tid] = v;
  __syncthreads();
  for (int off = 1; off < 1024; off <<= 1) {
    int t = (tid >= off) ? lds[tid - off] : 0;
    __syncthreads();
    lds[tid] += t;
    __syncthreads();
  }
  if (gid < n) excl[gid] = lds[tid] - v;
  if (tid == 1023) bsum[blockIdx.x] = lds[1023];
}

__global__ void scan2_k(int* __restrict__ bsum, int nb) {
  __shared__ int lds[128];
  int tid = threadIdx.x;
  int v = (tid < nb) ? bsum[tid] : 0;
  lds[tid] = v;
  __syncthreads();
  for (int off = 1; off < 128; off <<= 1) {
    int t = (tid >= off) ? lds[tid - off] : 0;
    __syncthreads();
    lds[tid] += t;
    __syncthreads();
  }
  if (tid < nb) bsum[tid] = lds[tid] - v;
}

// finalize: offs -> END offsets per node; inv = 1/max(deg,1)
__global__ __launch_bounds__(256) void scan3_k(int* __restrict__ excl,
                                               const int* __restrict__ bsum,
                                               const int* __restrict__ deg,
                                               float* __restrict__ inv, int n) {
  int gid = blockIdx.x * 256 + threadIdx.x;
  if (gid < n) {
    excl[gid] += bsum[gid >> 10] + deg[gid];
    inv[gid] = 1.0f / fmaxf((float)deg[gid], 1.0f);
  }
}

// ---------- per-sub-bucket LDS counting sort -> coalesced csr segment write ----------
__global__ __launch_bounds__(1024) void sort_emit_k(const unsigned* __restrict__ parts2,
                                                    const int* __restrict__ pcnt2,
                                                    const int* __restrict__ offs_end,
                                                    const int* __restrict__ degv,
                                                    int* __restrict__ csr) {
  __shared__ int cur[SUBN];
  __shared__ int sorted[CAP2];
  int sb = blockIdx.x;
  int n = min(pcnt2[sb], CAP2);
  const unsigned* p = parts2 + (size_t)sb * CAP2;
  int base = sb * SUBN;
  int segbase = offs_end[base] - degv[base];
  for (int i = threadIdx.x; i < SUBN; i += 1024) {
    int nd = base + i;
    cur[i] = (nd < NN) ? (offs_end[nd] - degv[nd]) : 0;
  }
  __syncthreads();
  for (int i = threadIdx.x; i < n; i += 1024) {
    unsigned v = p[i];
    int pos = atomicAdd(&cur[v >> 17], 1);
    sorted[pos - segbase] = (int)(v & 0x1FFFFu);
  }
  __syncthreads();
  for (int i = threadIdx.x; i < n; i += 1024) csr[segbase + i] = sorted[i];
}

// ---------- fp32 -> bf16 bulk convert ----------
__global__ __launch_bounds__(256) void tobf_k(const float* __restrict__ x,
                                              unsigned short* __restrict__ y, int n) {
  int idx = (blockIdx.x * 256 + threadIdx.x) * 4;
  if (idx < n) {
    float4 v = ld4(x + idx);
    unsigned int lo = (unsigned int)f2bf(v.x) | ((unsigned int)f2bf(v.y) << 16);
    unsigned int hi = (unsigned int)f2bf(v.z) | ((unsigned int)f2bf(v.w) << 16);
    *(uint2*)(y + idx) = make_uint2(lo, hi);
  }
}

__device__ inline void conv4(const float* s, unsigned short* d, int q) {
  float4 v = ld4(s + q * 4);
  unsigned int lo = (unsigned int)f2bf(v.x) | ((unsigned int)f2bf(v.y) << 16);
  unsigned int hi = (unsigned int)f2bf(v.z) | ((unsigned int)f2bf(v.w) << 16);
  ((uint2*)d)[q] = make_uint2(lo, hi);
}
__global__ __launch_bounds__(256) void wconv_k(const float* W1, const float* W2,
                                               const float* Wm1, const float* Wm2,
                                               const float* Wm3,
                                               unsigned short* W1bf, unsigned short* W2bf,
                                               unsigned short* Wm1bf, unsigned short* Wm2bf,
                                               unsigned short* Wm3bf) {
  int q = blockIdx.x * 256 + threadIdx.x;
  if (q < 4096) conv4(W1, W1bf, q);
  else if (q < 8192) conv4(W2, W2bf, q - 4096);
  else if (q < 16384) conv4(Wm1, Wm1bf, q - 8192);
  else if (q < 20480) conv4(Wm2, Wm2bf, q - 16384);
  else if (q < 24576) conv4(Wm3, Wm3bf, q - 20480);
}

// ---------- gather layer 1: 8-deep predicated pipeline ----------
__global__ __launch_bounds__(256) void gather1_k(const unsigned short* __restrict__ featbf,
                                                 const int* __restrict__ csr,
                                                 const int* __restrict__ offs_end,
                                                 const int* __restrict__ degv,
                                                 const float* __restrict__ inv,
                                                 unsigned short* __restrict__ agg1) {
  int v = blockIdx.x * 8 + (threadIdx.x >> 5);
  if (v >= NN) return;
  int lane = threadIdx.x & 31;
  int cnt = degv[v];
  int start = offs_end[v] - cnt;
  const uint2* fb = (const uint2*)featbf;
  float a0 = 0.f, a1 = 0.f, a2 = 0.f, a3 = 0.f;
  int nb8 = (cnt + 7) >> 3;
  for (int it = 0; it < nb8; ++it) {
    int b = start + (it << 3);
    int rem = cnt - (it << 3);
    int sidx[8]; float msk[8];
#pragma unroll
    for (int j = 0; j < 8; ++j) {
      bool ok = j < rem;
      sidx[j] = csr[b + (ok ? j : 0)];
      msk[j] = ok ? 1.f : 0.f;
    }
    uint2 x[8];
#pragma unroll
    for (int j = 0; j < 8; ++j) x[j] = fb[(size_t)sidx[j] * 32 + lane];
#pragma unroll
    for (int j = 0; j < 8; ++j) {
      a0 = fmaf(msk[j], bf2f((unsigned short)(x[j].x)), a0);
      a1 = fmaf(msk[j], bf2f((unsigned short)(x[j].x >> 16)), a1);
      a2 = fmaf(msk[j], bf2f((unsigned short)(x[j].y)), a2);
      a3 = fmaf(msk[j], bf2f((unsigned short)(x[j].y >> 16)), a3);
    }
  }
  float iv = inv[v];
  unsigned int lo = (unsigned int)f2bf(a0 * iv) | ((unsigned int)f2bf(a1 * iv) << 16);
  unsigned int hi = (unsigned int)f2bf(a2 * iv) | ((unsigned int)f2bf(a3 * iv) << 16);
  ((uint2*)agg1)[(size_t)v * 32 + lane] = make_uint2(lo, hi);
}

// ---------- gather layer 2 at masked nodes + bf16 concat ----------
__global__ __launch_bounds__(256) void gather2_k(const unsigned short* __restrict__ h1bf,
                                                 const unsigned short* __restrict__ featbf,
                                                 const int* __restrict__ masked,
                                                 const int* __restrict__ csr,
                                                 const int* __restrict__ offs_end,
                                                 const int* __restrict__ degv,
                                                 const float* __restrict__ inv,
                                                 unsigned short* __restrict__ agg2bf,
                                                 unsigned short* __restrict__ xcatbf) {
  int m = blockIdx.x * 8 + (threadIdx.x >> 5);
  if (m >= NM) return;
  int lane = threadIdx.x & 31;
  int v = masked[m];
  int cnt = degv[v];
  int start = offs_end[v] - cnt;
  const uint2* fb = (const uint2*)h1bf;
  float a0 = 0.f, a1 = 0.f, a2 = 0.f, a3 = 0.f;
  int nb8 = (cnt + 7) >> 3;
  for (int it = 0; it < nb8; ++it) {
    int b = start + (it << 3);
    int rem = cnt - (it << 3);
    int sidx[8]; float msk[8];
#pragma unroll
    for (int j = 0; j < 8; ++j) {
      bool ok = j < rem;
      sidx[j] = csr[b + (ok ? j : 0)];
      msk[j] = ok ? 1.f : 0.f;
    }
    uint2 x[8];
#pragma unroll
    for (int j = 0; j < 8; ++j) x[j] = fb[(size_t)sidx[j] * 32 + lane];
#pragma unroll
    for (int j = 0; j < 8; ++j) {
      a0 = fmaf(msk[j], bf2f((unsigned short)(x[j].x)), a0);
      a1 = fmaf(msk[j], bf2f((unsigned short)(x[j].x >> 16)), a1);
      a2 = fmaf(msk[j], bf2f((unsigned short)(x[j].y)), a2);
      a3 = fmaf(msk[j], bf2f((unsigned short)(x[j].y >> 16)), a3);
    }
  }
  float iv = inv[v];
  unsigned int lo = (unsigned int)f2bf(a0 * iv) | ((unsigned int)f2bf(a1 * iv) << 16);
  unsigned int hi = (unsigned int)f2bf(a2 * iv) | ((unsigned int)f2bf(a3 * iv) << 16);
  ((uint2*)agg2bf)[(size_t)m * 32 + lane] = make_uint2(lo, hi);
  ((uint2*)xcatbf)[(size_t)m * 64 + 32 + lane] = ((const uint2*)featbf)[(size_t)v * 32 + lane];
}

// ---------- generic bf16 MFMA GEMM ----------
template<int KT, bool BIAS, bool RELU, bool F32OUT>
__global__ __launch_bounds__(256) void mfma_gemm_k(const unsigned short* __restrict__ Abf,
                                                   const unsigned short* __restrict__ Wbf,
                                                   const float* __restrict__ bias,
                                                   void* __restrict__ Yout,
                                                   int ldy, int nrows) {
  const int lda = KT * 32;
  const int tid = threadIdx.x;
  const int wave = tid >> 6;
  const int lane = tid & 63;
  const int l15 = lane & 15;
  const int l4 = lane >> 4;
  const int rbase = blockIdx.x * 64;

  bf16x8 Bfr[2][KT];
#pragma unroll
  for (int c = 0; c < 2; ++c) {
    int col = (wave + 4 * c) * 16 + l15;
#pragma unroll
    for (int kt = 0; kt < KT; ++kt) {
      bf16x8 b;
#pragma unroll
      for (int i = 0; i < 8; ++i)
        b[i] = (short)Wbf[(kt * 32 + l4 * 8 + i) * 128 + col];
      Bfr[c][kt] = b;
    }
  }
  float bias0 = 0.f, bias1 = 0.f;
  if (BIAS) { bias0 = bias[wave * 16 + l15]; bias1 = bias[(wave + 4) * 16 + l15]; }

  for (int rsub = 0; rsub < 4; ++rsub) {
    int arow = rbase + rsub * 16 + l15;
    const unsigned short* ap = Abf + (size_t)(arow < nrows ? arow : 0) * lda;
    f32x4 acc0 = {0.f, 0.f, 0.f, 0.f};
    f32x4 acc1 = {0.f, 0.f, 0.f, 0.f};
#pragma unroll
    for (int kt = 0; kt < KT; ++kt) {
      bf16x8 a = *(const bf16x8*)(ap + kt * 32 + l4 * 8);
      acc0 = __builtin_amdgcn_mfma_f32_16x16x32_bf16(a, Bfr[0][kt], acc0, 0, 0, 0);
      acc1 = __builtin_amdgcn_mfma_f32_16x16x32_bf16(a, Bfr[1][kt], acc1, 0, 0, 0);
    }
#pragma unroll
    for (int r = 0; r < 4; ++r) {
      int orow = rbase + rsub * 16 + l4 * 4 + r;
      if (orow < nrows) {
        float v0 = acc0[r] + bias0, v1 = acc1[r] + bias1;
        if (RELU) { v0 = fmaxf(v0, 0.f); v1 = fmaxf(v1, 0.f); }
        if (F32OUT) {
          ((float*)Yout)[(size_t)orow * ldy + wave * 16 + l15] = v0;
          ((float*)Yout)[(size_t)orow * ldy + (wave + 4) * 16 + l15] = v1;
        } else {
          ((unsigned short*)Yout)[(size_t)orow * ldy + wave * 16 + l15] = f2bf(v0);
          ((unsigned short*)Yout)[(size_t)orow * ldy + (wave + 4) * 16 + l15] = f2bf(v1);
        }
      }
    }
  }
}

extern "C" void kernel_launch(void* const* d_in, const int* in_sizes, int n_in,
                              void* d_out, int out_size, void* d_ws, size_t ws_size,
                              hipStream_t stream) {
  const float* feat = (const float*)d_in[0];
  const int* src = (const int*)d_in[1];
  const int* dst = (const int*)d_in[2];
  const int* masked = (const int*)d_in[3];
  const float* W1 = (const float*)d_in[4];
  const float* b1 = (const float*)d_in[5];
  const float* W2 = (const float*)d_in[6];
  const float* b2 = (const float*)d_in[7];
  const float* Wm1 = (const float*)d_in[8];
  const float* bm1 = (const float*)d_in[9];
  const float* Wm2 = (const float*)d_in[10];
  const float* bm2 = (const float*)d_in[11];
  const float* Wm3 = (const float*)d_in[12];
  float* out = (float*)d_out;

  // ---- workspace layout ----
  char* p = (char*)d_ws;
  int* deg = (int*)p;              p += (size_t)NN * 4;
  int* offs = (int*)p;             p += (size_t)NN * 4;
  int* bsum = (int*)p;             p += 128 * 4;
  int* pcnt2 = (int*)p;            p += NSB * 4;
  float* inv = (float*)p;          p += (size_t)NN * 4;
  int* csr = (int*)p;              p += (size_t)NE * 4;
  p = (char*)(((size_t)p + 15) & ~(size_t)15);
  unsigned* parts2 = (unsigned*)p; p += (size_t)NSB * CAP2 * 4;
  p = (char*)(((size_t)p + 15) & ~(size_t)15);
  unsigned short* featbf = (unsigned short*)p;  p += (size_t)NN * 128 * 2;
  unsigned short* agg1 = (unsigned short*)p;    p += (size_t)NN * 128 * 2;
  unsigned short* h1bf = (unsigned short*)p;    p += (size_t)NN * 128 * 2;
  unsigned short* W1bf = (unsigned short*)p;    p += 16384 * 2;
  unsigned short* W2bf = (unsigned short*)p;    p += 16384 * 2;
  unsigned short* Wm1bf = (unsigned short*)p;   p += 32768 * 2;
  unsigned short* Wm2bf = (unsigned short*)p;   p += 16384 * 2;
  unsigned short* Wm3bf = (unsigned short*)p;   p += 16384 * 2;
  p = (char*)(((size_t)p + 15) & ~(size_t)15);
  unsigned short* agg2bf = (unsigned short*)p;  p += (size_t)NM * 128 * 2;
  unsigned short* xcatbf = (unsigned short*)p;  p += (size_t)NM * 256 * 2;
  unsigned short* y1bf = (unsigned short*)p;    p += (size_t)NM * 128 * 2;
  unsigned short* y2bf = (unsigned short*)p;    p += (size_t)NM * 128 * 2;

  (void)hipMemsetAsync(pcnt2, 0, NSB * 4, stream);

  // sparse build: 256-way partition -> histogram -> scan -> LDS counting sort
  part2_k<<<(NE + PCH - 1) / PCH, 256, 0, stream>>>(src, dst, parts2, pcnt2);
  deg2_k<<<NSB, 1024, 0, stream>>>(parts2, pcnt2, deg);
  int nb = (NN + 1023) / 1024;
  scan1_k<<<nb, 1024, 0, stream>>>(deg, offs, bsum, NN);
  scan2_k<<<1, 128, 0, stream>>>(bsum, nb);
  scan3_k<<<(NN + 255) / 256, 256, 0, stream>>>(offs, bsum, deg, inv, NN);
  sort_emit_k<<<NSB, 1024, 0, stream>>>(parts2, pcnt2, offs, deg, csr);

  // bf16 conversions
  tobf_k<<<(NN * 128 / 4 + 255) / 256, 256, 0, stream>>>(feat, featbf, NN * 128);
  wconv_k<<<96, 256, 0, stream>>>(W1, W2, Wm1, Wm2, Wm3, W1bf, W2bf, Wm1bf, Wm2bf, Wm3bf);

  // GCN layer 1
  gather1_k<<<(NN + 7) / 8, 256, 0, stream>>>(featbf, csr, offs, deg, inv, agg1);
  mfma_gemm_k<4, true, true, false><<<(NN + 63) / 64, 256, 0, stream>>>(agg1, W1bf, b1, h1bf, 128, NN);

  // GCN layer 2 at masked nodes + concat
  gather2_k<<<(NM + 7) / 8, 256, 0, stream>>>(h1bf, featbf, masked, csr, offs, deg, inv, agg2bf, xcatbf);
  int gm = (NM + 63) / 64;
  mfma_gemm_k<4, true, true, false><<<gm, 256, 0, stream>>>(agg2bf, W2bf, b2, xcatbf, 256, NM);

  // MLP head (bf16 MFMA)
  mfma_gemm_k<8, true, true, false><<<gm, 256, 0, stream>>>(xcatbf, Wm1bf, bm1, y1bf, 128, NM);
  mfma_gemm_k<4, true, true, false><<<gm, 256, 0, stream>>>(y1bf, Wm2bf, bm2, y2bf, 128, NM);
  mfma_gemm_k<4, false, false, true><<<gm, 256, 0, stream>>>(y2bf, Wm3bf, nullptr, out, 128, NM);
}

// Round 8
// 175.066 us; speedup vs baseline: 3.0731x; 1.0364x over previous
//
#include <hip/hip_runtime.h>

#define NN 100000
#define NE 1600000
#define NM 10000
#define NSB 256
#define SUBN 391          // nodes per sub-bucket; 256*391 = 100096 >= NN
#define CAP2 7424         // per-sub-bucket edge capacity (mean 6251, sigma 79)
#define PCH 2048

typedef __attribute__((ext_vector_type(8))) short bf16x8;
typedef __attribute__((ext_vector_type(4))) float f32x4;

__device__ inline float4 ld4(const float* p) { return *(const float4*)p; }
__device__ inline float bf2f(unsigned short u) {
  union { unsigned int i; float f; } c; c.i = ((unsigned int)u) << 16; return c.f;
}
__device__ inline unsigned short f2bf(float f) {
  union { float f; unsigned int i; } c; c.f = f;
  unsigned int u = c.i + 0x7fffu + ((c.i >> 16) & 1u);
  return (unsigned short)(u >> 16);
}
// swizzled LDS store of one bf16 at (row, col); rowBytes = 256 or 512
__device__ inline void stx(unsigned char* base, int rowBytes, int row, int col,
                           unsigned short val) {
  int bc = col * 2;
  int c = bc >> 4, cp = c ^ (row & 15);
  *(unsigned short*)&base[row * rowBytes + (cp << 4) + (bc & 15)] = val;
}
// swizzled LDS 16B fragment read at (row, 16B-chunk kc)
__device__ inline bf16x8 ldx8(const unsigned char* base, int rowBytes, int row, int kc) {
  return *(const bf16x8*)&base[row * rowBytes + ((kc ^ (row & 15)) << 4)];
}

// ---------- 256-way edge partition, coalesced appends ----------
__global__ __launch_bounds__(256) void part2_k(const int* __restrict__ src,
                                               const int* __restrict__ dst,
                                               unsigned* __restrict__ parts2,
                                               int* __restrict__ pcnt2) {
  __shared__ int cntw[4][NSB];
  __shared__ int basew[4][NSB];
  __shared__ int bstart[NSB + 1];
  __shared__ int gbase[NSB];
  __shared__ int wsum[4];
  __shared__ unsigned buf[PCH];
  __shared__ unsigned char bb[PCH];
  const int tid = threadIdx.x;
  const int wv = tid >> 6;
  const int e0 = blockIdx.x * PCH;

  for (int i = tid; i < 4 * NSB; i += 256) ((int*)cntw)[i] = 0;
  __syncthreads();

  unsigned pk[8];
  int b_[8], lp_[8];
#pragma unroll
  for (int j = 0; j < 8; ++j) {
    int e = e0 + j * 256 + tid;
    bool ok = e < NE;
    int s = ok ? src[e] : 0;
    int d = ok ? dst[e] : 0;
    int b = d / SUBN;
    int ld = d - b * SUBN;
    pk[j] = ((unsigned)ld << 17) | (unsigned)s;
    b_[j] = ok ? b : -1;
    if (ok) lp_[j] = atomicAdd(&cntw[wv][b], 1);
  }
  __syncthreads();
  int t0 = cntw[0][tid], t1 = cntw[1][tid], t2 = cntw[2][tid], t3 = cntw[3][tid];
  int tot = t0 + t1 + t2 + t3;
  int x = tot;
#pragma unroll
  for (int d = 1; d < 64; d <<= 1) {
    int y = __shfl_up(x, d, 64);
    if ((tid & 63) >= d) x += y;
  }
  if ((tid & 63) == 63) wsum[wv] = x;
  __syncthreads();
  int woff = 0;
#pragma unroll
  for (int w = 0; w < 4; ++w) woff += (w < wv) ? wsum[w] : 0;
  int excl = x + woff - tot;
  bstart[tid] = excl;
  basew[0][tid] = excl;
  basew[1][tid] = excl + t0;
  basew[2][tid] = excl + t0 + t1;
  basew[3][tid] = excl + t0 + t1 + t2;
  gbase[tid] = atomicAdd(&pcnt2[tid], tot);
  if (tid == NSB - 1) bstart[NSB] = excl + tot;
  __syncthreads();
#pragma unroll
  for (int j = 0; j < 8; ++j)
    if (b_[j] >= 0) {
      int pos = basew[wv][b_[j]] + lp_[j];
      buf[pos] = pk[j];
      bb[pos] = (unsigned char)b_[j];
    }
  __syncthreads();
  int total = bstart[NSB];
  for (int i = tid; i < total; i += 256) {
    int b = bb[i];
    int gi = gbase[b] + (i - bstart[b]);
    if (gi < CAP2) parts2[(size_t)b * CAP2 + gi] = buf[i];
  }
}

// ---------- per-sub-bucket degree histogram ----------
__global__ __launch_bounds__(1024) void deg2_k(const unsigned* __restrict__ parts2,
                                               const int* __restrict__ pcnt2,
                                               int* __restrict__ deg) {
  __shared__ int cnt[SUBN];
  int sb = blockIdx.x;
  int n = min(pcnt2[sb], CAP2);
  const unsigned* p = parts2 + (size_t)sb * CAP2;
  for (int i = threadIdx.x; i < SUBN; i += 1024) cnt[i] = 0;
  __syncthreads();
  for (int i = threadIdx.x; i < n; i += 1024) atomicAdd(&cnt[p[i] >> 17], 1);
  __syncthreads();
  int base = sb * SUBN;
  for (int i = threadIdx.x; i < SUBN; i += 1024)
    if (base + i < NN) deg[base + i] = cnt[i];
}

__global__ __launch_bounds__(1024) void scan1_k(const int* __restrict__ deg,
                                                int* __restrict__ excl,
                                                int* __restrict__ bsum, int n) {
  __shared__ int lds[1024];
  int tid = threadIdx.x;
  int gid = blockIdx.x * 1024 + tid;
  int v = (gid < n) ? deg[gid] : 0;
  lds[tid] = v;
  __syncthreads();
  for (int off = 1; off < 1024; off <<= 1) {
    int t = (tid >= off) ? lds[tid - off] : 0;
    __syncthreads();
    lds[tid] += t;
    __syncthreads();
  }
  if (gid < n) excl[gid] = lds[tid] - v;
  if (tid == 1023) bsum[blockIdx.x] = lds[1023];
}

__global__ void scan2_k(int* __restrict__ bsum, int nb) {
  __shared__ int lds[128];
  int tid = threadIdx.x;
  int v = (tid < nb) ? bsum[tid] : 0;
  lds[tid] = v;
  __syncthreads();
  for (int off = 1; off < 128; off <<= 1) {
    int t = (tid >= off) ? lds[tid - off] : 0;
    __syncthreads();
    lds[tid] += t;
    __syncthreads();
  }
  if (tid < nb) bsum[tid] = lds[tid] - v;
}

// finalize: offs -> END offsets per node; inv = 1/max(deg,1)
__global__ __launch_bounds__(256) void scan3_k(int* __restrict__ excl,
                                               const int* __restrict__ bsum,
                                               const int* __restrict__ deg,
                                               float* __restrict__ inv, int n) {
  int gid = blockIdx.x * 256 + threadIdx.x;
  if (gid < n) {
    excl[gid] += bsum[gid >> 10] + deg[gid];
    inv[gid] = 1.0f / fmaxf((float)deg[gid], 1.0f);
  }
}

// ---------- per-sub-bucket LDS counting sort -> coalesced csr segment ----------
__global__ __launch_bounds__(1024) void sort_emit_k(const unsigned* __restrict__ parts2,
                                                    const int* __restrict__ pcnt2,
                                                    const int* __restrict__ offs_end,
                                                    const int* __restrict__ degv,
                                                    int* __restrict__ csr) {
  __shared__ int cur[SUBN];
  __shared__ int sorted[CAP2];
  int sb = blockIdx.x;
  int n = min(pcnt2[sb], CAP2);
  const unsigned* p = parts2 + (size_t)sb * CAP2;
  int base = sb * SUBN;
  int segbase = offs_end[base] - degv[base];
  for (int i = threadIdx.x; i < SUBN; i += 1024) {
    int nd = base + i;
    cur[i] = (nd < NN) ? (offs_end[nd] - degv[nd]) : 0;
  }
  __syncthreads();
  for (int i = threadIdx.x; i < n; i += 1024) {
    unsigned v = p[i];
    int pos = atomicAdd(&cur[v >> 17], 1);
    sorted[pos - segbase] = (int)(v & 0x1FFFFu);
  }
  __syncthreads();
  for (int i = threadIdx.x; i < n; i += 1024) csr[segbase + i] = sorted[i];
}

// ---------- fp32 -> bf16 bulk convert ----------
__global__ __launch_bounds__(256) void tobf_k(const float* __restrict__ x,
                                              unsigned short* __restrict__ y, int n) {
  int idx = (blockIdx.x * 256 + threadIdx.x) * 4;
  if (idx < n) {
    float4 v = ld4(x + idx);
    unsigned int lo = (unsigned int)f2bf(v.x) | ((unsigned int)f2bf(v.y) << 16);
    unsigned int hi = (unsigned int)f2bf(v.z) | ((unsigned int)f2bf(v.w) << 16);
    *(uint2*)(y + idx) = make_uint2(lo, hi);
  }
}

// ---------- weights -> bf16 in MFMA fragment layout ----------
// Wf[((k>>3)*128 + col)*8 + (k&7)] = bf16(W[k][col])
__device__ inline void convfrag(const float* W, unsigned short* Wf, int g) {
  int k8 = (g >> 7) << 3, col = g & 127;
  unsigned short tmp[8];
#pragma unroll
  for (int i = 0; i < 8; ++i) tmp[i] = f2bf(W[(k8 + i) * 128 + col]);
  *(uint4*)&Wf[(size_t)g * 8] = *(const uint4*)tmp;
}
__global__ __launch_bounds__(256) void wconv_k(const float* W1, const float* W2,
                                               const float* Wm1, const float* Wm2,
                                               const float* Wm3,
                                               unsigned short* W1f, unsigned short* W2f,
                                               unsigned short* Wm1f, unsigned short* Wm2f,
                                               unsigned short* Wm3f) {
  int g = blockIdx.x * 256 + threadIdx.x;   // 12288 groups total
  if (g < 2048) convfrag(W1, W1f, g);
  else if (g < 4096) convfrag(W2, W2f, g - 2048);
  else if (g < 8192) convfrag(Wm1, Wm1f, g - 4096);
  else if (g < 10240) convfrag(Wm2, Wm2f, g - 8192);
  else if (g < 12288) convfrag(Wm3, Wm3f, g - 10240);
}

// ---------- mark nodes whose h1 is consumed by layer 2 ----------
__global__ __launch_bounds__(256) void mark_k(const int* __restrict__ masked,
                                              const int* __restrict__ csr,
                                              const int* __restrict__ offs_end,
                                              const int* __restrict__ degv,
                                              unsigned char* __restrict__ needed) {
  int m = blockIdx.x * 8 + (threadIdx.x >> 5);
  if (m >= NM) return;
  int lane = threadIdx.x & 31;
  int v = masked[m];
  int cnt = degv[v];
  int start = offs_end[v] - cnt;
  for (int i = lane; i < cnt; i += 32) needed[csr[start + i]] = 1;
}

// ---------- fused layer 1: gather(feat) -> LDS -> MFMA(W1) -> h1bf ----------
__global__ __launch_bounds__(256) void fused_l1_k(const unsigned short* __restrict__ featbf,
                                                  const int* __restrict__ csr,
                                                  const int* __restrict__ offs_end,
                                                  const int* __restrict__ degv,
                                                  const float* __restrict__ inv,
                                                  const unsigned char* __restrict__ needed,
                                                  const unsigned short* __restrict__ W1f,
                                                  const float* __restrict__ b1,
                                                  unsigned short* __restrict__ h1bf) {
  __shared__ unsigned char lds[64 * 256];   // 64 agg rows, bf16, swizzled
  const int tid = threadIdx.x;
  const int rbase = blockIdx.x * 64;
  // ---- gather phase: 8 groups x 8 nodes ----
  {
    int grp = tid >> 5, lane = tid & 31;
    const uint2* fb = (const uint2*)featbf;
    int c = lane >> 1;
    for (int k = 0; k < 8; ++k) {
      int row = grp * 8 + k;
      int v = rbase + row;
      unsigned char* dstp = &lds[row * 256 + (((c ^ (row & 15)) << 4)) + (lane & 1) * 8];
      if (v >= NN || !needed[v]) { *(uint2*)dstp = make_uint2(0u, 0u); continue; }
      int cnt = degv[v];
      int start = offs_end[v] - cnt;
      float a0 = 0.f, a1 = 0.f, a2 = 0.f, a3 = 0.f;
      int nb8 = (cnt + 7) >> 3;
      for (int it = 0; it < nb8; ++it) {
        int b = start + (it << 3);
        int rem = cnt - (it << 3);
        int sidx[8]; float msk[8];
#pragma unroll
        for (int j = 0; j < 8; ++j) {
          bool ok = j < rem;
          sidx[j] = csr[b + (ok ? j : 0)];
          msk[j] = ok ? 1.f : 0.f;
        }
        uint2 x[8];
#pragma unroll
        for (int j = 0; j < 8; ++j) x[j] = fb[(size_t)sidx[j] * 32 + lane];
#pragma unroll
        for (int j = 0; j < 8; ++j) {
          a0 = fmaf(msk[j], bf2f((unsigned short)(x[j].x)), a0);
          a1 = fmaf(msk[j], bf2f((unsigned short)(x[j].x >> 16)), a1);
          a2 = fmaf(msk[j], bf2f((unsigned short)(x[j].y)), a2);
          a3 = fmaf(msk[j], bf2f((unsigned short)(x[j].y >> 16)), a3);
        }
      }
      float iv = inv[v];
      unsigned int lo = (unsigned int)f2bf(a0 * iv) | ((unsigned int)f2bf(a1 * iv) << 16);
      unsigned int hi = (unsigned int)f2bf(a2 * iv) | ((unsigned int)f2bf(a3 * iv) << 16);
      *(uint2*)dstp = make_uint2(lo, hi);
    }
  }
  __syncthreads();
  // ---- MFMA phase: h1 = relu(agg @ W1 + b1) ----
  const int wave = tid >> 6, lane = tid & 63, l15 = lane & 15, l4 = lane >> 4;
  int col0 = wave * 16 + l15, col1 = (wave + 4) * 16 + l15;
  float bias0 = b1[col0], bias1 = b1[col1];
  for (int rsub = 0; rsub < 4; ++rsub) {
    int row = rsub * 16 + l15;
    f32x4 acc0 = {0.f, 0.f, 0.f, 0.f};
    f32x4 acc1 = {0.f, 0.f, 0.f, 0.f};
#pragma unroll
    for (int kt = 0; kt < 4; ++kt) {
      int kc = kt * 4 + l4;
      bf16x8 a = ldx8(lds, 256, row, kc);
      bf16x8 b0 = *(const bf16x8*)&W1f[((size_t)kc * 128 + col0) * 8];
      bf16x8 b1v = *(const bf16x8*)&W1f[((size_t)kc * 128 + col1) * 8];
      acc0 = __builtin_amdgcn_mfma_f32_16x16x32_bf16(a, b0, acc0, 0, 0, 0);
      acc1 = __builtin_amdgcn_mfma_f32_16x16x32_bf16(a, b1v, acc1, 0, 0, 0);
    }
#pragma unroll
    for (int r = 0; r < 4; ++r) {
      int orow = rbase + rsub * 16 + l4 * 4 + r;
      if (orow < NN) {
        h1bf[(size_t)orow * 128 + col0] = f2bf(fmaxf(acc0[r] + bias0, 0.f));
        h1bf[(size_t)orow * 128 + col1] = f2bf(fmaxf(acc1[r] + bias1, 0.f));
      }
    }
  }
}

// ---------- gather layer 2 at masked nodes (agg2 only) ----------
__global__ __launch_bounds__(256) void gather2_k(const unsigned short* __restrict__ h1bf,
                                                 const int* __restrict__ masked,
                                                 const int* __restrict__ csr,
                                                 const int* __restrict__ offs_end,
                                                 const int* __restrict__ degv,
                                                 const float* __restrict__ inv,
                                                 unsigned short* __restrict__ agg2bf) {
  int m = blockIdx.x * 8 + (threadIdx.x >> 5);
  if (m >= NM) return;
  int lane = threadIdx.x & 31;
  int v = masked[m];
  int cnt = degv[v];
  int start = offs_end[v] - cnt;
  const uint2* fb = (const uint2*)h1bf;
  float a0 = 0.f, a1 = 0.f, a2 = 0.f, a3 = 0.f;
  int nb8 = (cnt + 7) >> 3;
  for (int it = 0; it < nb8; ++it) {
    int b = start + (it << 3);
    int rem = cnt - (it << 3);
    int sidx[8]; float msk[8];
#pragma unroll
    for (int j = 0; j < 8; ++j) {
      bool ok = j < rem;
      sidx[j] = csr[b + (ok ? j : 0)];
      msk[j] = ok ? 1.f : 0.f;
    }
    uint2 x[8];
#pragma unroll
    for (int j = 0; j < 8; ++j) x[j] = fb[(size_t)sidx[j] * 32 + lane];
#pragma unroll
    for (int j = 0; j < 8; ++j) {
      a0 = fmaf(msk[j], bf2f((unsigned short)(x[j].x)), a0);
      a1 = fmaf(msk[j], bf2f((unsigned short)(x[j].x >> 16)), a1);
      a2 = fmaf(msk[j], bf2f((unsigned short)(x[j].y)), a2);
      a3 = fmaf(msk[j], bf2f((unsigned short)(x[j].y >> 16)), a3);
    }
  }
  float iv = inv[v];
  unsigned int lo = (unsigned int)f2bf(a0 * iv) | ((unsigned int)f2bf(a1 * iv) << 16);
  unsigned int hi = (unsigned int)f2bf(a2 * iv) | ((unsigned int)f2bf(a3 * iv) << 16);
  ((uint2*)agg2bf)[(size_t)m * 32 + lane] = make_uint2(lo, hi);
}

// ---------- fused head: xcat build + 3-layer MLP, all tiles LDS-resident ----------
__global__ __launch_bounds__(256) void mlp_fused_k(const unsigned short* __restrict__ agg2bf,
                                                   const unsigned short* __restrict__ featbf,
                                                   const int* __restrict__ masked,
                                                   const unsigned short* __restrict__ W2f,
                                                   const float* __restrict__ b2,
                                                   const unsigned short* __restrict__ Wm1f,
                                                   const float* __restrict__ bm1,
                                                   const unsigned short* __restrict__ Wm2f,
                                                   const float* __restrict__ bm2,
                                                   const unsigned short* __restrict__ Wm3f,
                                                   float* __restrict__ out) {
  __shared__ unsigned char ldsX[64 * 512];   // xcat tile / y2 tile
  __shared__ unsigned char ldsY[64 * 256];   // y1 tile
  const int tid = threadIdx.x;
  const int rbase = blockIdx.x * 64;
  const int wave = tid >> 6, lane = tid & 63, l15 = lane & 15, l4 = lane >> 4;
  // ---- phase 0a: feat half of xcat (cols 128..255) ----
  {
    int grp = tid >> 5, ln = tid & 31;
    uint2 vals[8];
#pragma unroll
    for (int k = 0; k < 8; ++k) {
      int m = rbase + grp * 8 + k;
      vals[k] = make_uint2(0u, 0u);
      if (m < NM) {
        int v = masked[m];
        vals[k] = ((const uint2*)featbf)[(size_t)v * 32 + ln];
      }
    }
#pragma unroll
    for (int k = 0; k < 8; ++k) {
      int row = grp * 8 + k;
      int c = 16 + (ln >> 1);
      *(uint2*)&ldsX[row * 512 + ((c ^ (row & 15)) << 4) + (ln & 1) * 8] = vals[k];
    }
  }
  // ---- phase 0b: left half = relu(agg2 @ W2 + b2), A from global ----
  {
    int col0 = wave * 16 + l15, col1 = (wave + 4) * 16 + l15;
    float bias0 = b2[col0], bias1 = b2[col1];
    for (int rsub = 0; rsub < 4; ++rsub) {
      int arow = rbase + rsub * 16 + l15;
      const unsigned short* ap = agg2bf + (size_t)min(arow, NM - 1) * 128;
      f32x4 acc0 = {0.f, 0.f, 0.f, 0.f};
      f32x4 acc1 = {0.f, 0.f, 0.f, 0.f};
#pragma unroll
      for (int kt = 0; kt < 4; ++kt) {
        int kc = kt * 4 + l4;
        bf16x8 a = *(const bf16x8*)(ap + kc * 8);
        bf16x8 b0 = *(const bf16x8*)&W2f[((size_t)kc * 128 + col0) * 8];
        bf16x8 b1v = *(const bf16x8*)&W2f[((size_t)kc * 128 + col1) * 8];
        acc0 = __builtin_amdgcn_mfma_f32_16x16x32_bf16(a, b0, acc0, 0, 0, 0);
        acc1 = __builtin_amdgcn_mfma_f32_16x16x32_bf16(a, b1v, acc1, 0, 0, 0);
      }
#pragma unroll
      for (int r = 0; r < 4; ++r) {
        int row = rsub * 16 + l4 * 4 + r;
        stx(ldsX, 512, row, col0, f2bf(fmaxf(acc0[r] + bias0, 0.f)));
        stx(ldsX, 512, row, col1, f2bf(fmaxf(acc1[r] + bias1, 0.f)));
      }
    }
  }
  __syncthreads();
  // ---- phase 1: y1 = relu(xcat @ Wm1 + bm1), K=256 ----
  {
    int col0 = wave * 16 + l15, col1 = (wave + 4) * 16 + l15;
    float bias0 = bm1[col0], bias1 = bm1[col1];
    for (int rsub = 0; rsub < 4; ++rsub) {
      int row = rsub * 16 + l15;
      f32x4 acc0 = {0.f, 0.f, 0.f, 0.f};
      f32x4 acc1 = {0.f, 0.f, 0.f, 0.f};
#pragma unroll
      for (int kt = 0; kt < 8; ++kt) {
        int kc = kt * 4 + l4;
        bf16x8 a = ldx8(ldsX, 512, row, kc);
        bf16x8 b0 = *(const bf16x8*)&Wm1f[((size_t)kc * 128 + col0) * 8];
        bf16x8 b1v = *(const bf16x8*)&Wm1f[((size_t)kc * 128 + col1) * 8];
        acc0 = __builtin_amdgcn_mfma_f32_16x16x32_bf16(a, b0, acc0, 0, 0, 0);
        acc1 = __builtin_amdgcn_mfma_f32_16x16x32_bf16(a, b1v, acc1, 0, 0, 0);
      }
#pragma unroll
      for (int r = 0; r < 4; ++r) {
        int row2 = rsub * 16 + l4 * 4 + r;
        stx(ldsY, 256, row2, col0, f2bf(fmaxf(acc0[r] + bias0, 0.f)));
        stx(ldsY, 256, row2, col1, f2bf(fmaxf(acc1[r] + bias1, 0.f)));
      }
    }
  }
  __syncthreads();
  // ---- phase 2: y2 = relu(y1 @ Wm2 + bm2) -> ldsX (as 256B rows) ----
  {
    int col0 = wave * 16 + l15, col1 = (wave + 4) * 16 + l15;
    float bias0 = bm2[col0], bias1 = bm2[col1];
    for (int rsub = 0; rsub < 4; ++rsub) {
      int row = rsub * 16 + l15;
      f32x4 acc0 = {0.f, 0.f, 0.f, 0.f};
      f32x4 acc1 = {0.f, 0.f, 0.f, 0.f};
#pragma unroll
      for (int kt = 0; kt < 4; ++kt) {
        int kc = kt * 4 + l4;
        bf16x8 a = ldx8(ldsY, 256, row, kc);
        bf16x8 b0 = *(const bf16x8*)&Wm2f[((size_t)kc * 128 + col0) * 8];
        bf16x8 b1v = *(const bf16x8*)&Wm2f[((size_t)kc * 128 + col1) * 8];
        acc0 = __builtin_amdgcn_mfma_f32_16x16x32_bf16(a, b0, acc0, 0, 0, 0);
        acc1 = __builtin_amdgcn_mfma_f32_16x16x32_bf16(a, b1v, acc1, 0, 0, 0);
      }
#pragma unroll
      for (int r = 0; r < 4; ++r) {
        int row2 = rsub * 16 + l4 * 4 + r;
        stx(ldsX, 256, row2, col0, f2bf(fmaxf(acc0[r] + bias0, 0.f)));
        stx(ldsX, 256, row2, col1, f2bf(fmaxf(acc1[r] + bias1, 0.f)));
      }
    }
  }
  __syncthreads();
  // ---- phase 3: out = y2 @ Wm3, fp32 global ----
  {
    int col0 = wave * 16 + l15, col1 = (wave + 4) * 16 + l15;
    for (int rsub = 0; rsub < 4; ++rsub) {
      int row = rsub * 16 + l15;
      f32x4 acc0 = {0.f, 0.f, 0.f, 0.f};
      f32x4 acc1 = {0.f, 0.f, 0.f, 0.f};
#pragma unroll
      for (int kt = 0; kt < 4; ++kt) {
        int kc = kt * 4 + l4;
        bf16x8 a = ldx8(ldsX, 256, row, kc);
        bf16x8 b0 = *(const bf16x8*)&Wm3f[((size_t)kc * 128 + col0) * 8];
        bf16x8 b1v = *(const bf16x8*)&Wm3f[((size_t)kc * 128 + col1) * 8];
        acc0 = __builtin_amdgcn_mfma_f32_16x16x32_bf16(a, b0, acc0, 0, 0, 0);
        acc1 = __builtin_amdgcn_mfma_f32_16x16x32_bf16(a, b1v, acc1, 0, 0, 0);
      }
#pragma unroll
      for (int r = 0; r < 4; ++r) {
        int orow = rbase + rsub * 16 + l4 * 4 + r;
        if (orow < NM) {
          out[(size_t)orow * 128 + col0] = acc0[r];
          out[(size_t)orow * 128 + col1] = acc1[r];
        }
      }
    }
  }
}

extern "C" void kernel_launch(void* const* d_in, const int* in_sizes, int n_in,
                              void* d_out, int out_size, void* d_ws, size_t ws_size,
                              hipStream_t stream) {
  const float* feat = (const float*)d_in[0];
  const int* src = (const int*)d_in[1];
  const int* dst = (const int*)d_in[2];
  const int* masked = (const int*)d_in[3];
  const float* W1 = (const float*)d_in[4];
  const float* b1 = (const float*)d_in[5];
  const float* W2 = (const float*)d_in[6];
  const float* b2 = (const float*)d_in[7];
  const float* Wm1 = (const float*)d_in[8];
  const float* bm1 = (const float*)d_in[9];
  const float* Wm2 = (const float*)d_in[10];
  const float* bm2 = (const float*)d_in[11];
  const float* Wm3 = (const float*)d_in[12];
  float* out = (float*)d_out;

  // ---- workspace layout ----
  char* p = (char*)d_ws;
  int* deg = (int*)p;              p += (size_t)NN * 4;
  int* offs = (int*)p;             p += (size_t)NN * 4;
  int* bsum = (int*)p;             p += 128 * 4;
  int* pcnt2 = (int*)p;            p += NSB * 4;
  float* inv = (float*)p;          p += (size_t)NN * 4;
  int* csr = (int*)p;              p += (size_t)NE * 4;
  unsigned char* needed = (unsigned char*)p; p += (size_t)NN;
  p = (char*)(((size_t)p + 15) & ~(size_t)15);
  unsigned* parts2 = (unsigned*)p; p += (size_t)NSB * CAP2 * 4;
  unsigned short* featbf = (unsigned short*)p;  p += (size_t)NN * 128 * 2;
  unsigned short* h1bf = (unsigned short*)p;    p += (size_t)NN * 128 * 2;
  unsigned short* agg2bf = (unsigned short*)p;  p += (size_t)NM * 128 * 2;
  unsigned short* W1f = (unsigned short*)p;     p += 16384 * 2;
  unsigned short* W2f = (unsigned short*)p;     p += 16384 * 2;
  unsigned short* Wm1f = (unsigned short*)p;    p += 32768 * 2;
  unsigned short* Wm2f = (unsigned short*)p;    p += 16384 * 2;
  unsigned short* Wm3f = (unsigned short*)p;    p += 16384 * 2;

  (void)hipMemsetAsync(pcnt2, 0, NSB * 4, stream);
  (void)hipMemsetAsync(needed, 0, NN, stream);

  // sparse build: 256-way partition -> histogram -> scan -> LDS counting sort
  part2_k<<<(NE + PCH - 1) / PCH, 256, 0, stream>>>(src, dst, parts2, pcnt2);
  deg2_k<<<NSB, 1024, 0, stream>>>(parts2, pcnt2, deg);
  int nb = (NN + 1023) / 1024;
  scan1_k<<<nb, 1024, 0, stream>>>(deg, offs, bsum, NN);
  scan2_k<<<1, 128, 0, stream>>>(bsum, nb);
  scan3_k<<<(NN + 255) / 256, 256, 0, stream>>>(offs, bsum, deg, inv, NN);
  sort_emit_k<<<NSB, 1024, 0, stream>>>(parts2, pcnt2, offs, deg, csr);

  // bf16 conversions (feat + fragment-layout weights)
  tobf_k<<<(NN * 128 / 4 + 255) / 256, 256, 0, stream>>>(feat, featbf, NN * 128);
  wconv_k<<<48, 256, 0, stream>>>(W1, W2, Wm1, Wm2, Wm3, W1f, W2f, Wm1f, Wm2f, Wm3f);

  // mark nodes needed by layer 2
  mark_k<<<(NM + 7) / 8, 256, 0, stream>>>(masked, csr, offs, deg, needed);

  // fused GCN layer 1 (gather + MFMA)
  fused_l1_k<<<(NN + 63) / 64, 256, 0, stream>>>(featbf, csr, offs, deg, inv, needed,
                                                 W1f, b1, h1bf);
  // layer-2 aggregation at masked nodes
  gather2_k<<<(NM + 7) / 8, 256, 0, stream>>>(h1bf, masked, csr, offs, deg, inv, agg2bf);

  // fused head: [relu(agg2@W2+b2), feat] -> 3-layer MLP -> out
  mlp_fused_k<<<(NM + 63) / 64, 256, 0, stream>>>(agg2bf, featbf, masked,
                                                  W2f, b2, Wm1f, bm1, Wm2f, bm2, Wm3f, out);
}